// Round 14
// baseline (848.647 us; speedup 1.0000x reference)
//
#include <hip/hip_runtime.h>
#include <hip/hip_fp16.h>

typedef unsigned short u16;
typedef unsigned int u32;
typedef __attribute__((ext_vector_type(8))) short short8;
typedef __attribute__((ext_vector_type(4))) float f32x4;

#define NN 50000
#define EE 800000
#define SCAN_B 49   // 49 blocks x 1024 = 50176 >= NN

__device__ __forceinline__ float bf2f(u16 u){ union{u32 i; float f;} v; v.i=((u32)u)<<16; return v.f; }
__device__ __forceinline__ u16 f2bf(float f){ union{float f; u32 i;} v; v.f=f; u32 b=v.i; b += 0x7FFFu + ((b>>16)&1u); return (u16)(b>>16); }
__device__ __forceinline__ float sigmoidf_(float x){ return 1.0f/(1.0f+__expf(-x)); }

__device__ __forceinline__ void cvt8(uint4 q, float* f){
  f[0]=bf2f((u16)(q.x&0xFFFF)); f[1]=bf2f((u16)(q.x>>16));
  f[2]=bf2f((u16)(q.y&0xFFFF)); f[3]=bf2f((u16)(q.y>>16));
  f[4]=bf2f((u16)(q.z&0xFFFF)); f[5]=bf2f((u16)(q.z>>16));
  f[6]=bf2f((u16)(q.w&0xFFFF)); f[7]=bf2f((u16)(q.w>>16));
}
// R11: hardware packed f32->bf16 convert (RNE, identical to f2bf rounding).
__device__ __forceinline__ u32 cvtpk_bf16(float lo, float hi){
  u32 r; asm("v_cvt_pk_bf16_f32 %0, %1, %2" : "=v"(r) : "v"(lo), "v"(hi)); return r;
}
__device__ __forceinline__ uint4 pack8(const float* f){
  uint4 q;
  q.x=cvtpk_bf16(f[0],f[1]);
  q.y=cvtpk_bf16(f[2],f[3]);
  q.z=cvtpk_bf16(f[4],f[5]);
  q.w=cvtpk_bf16(f[6],f[7]);
  return q;
}

// f16 helpers for the packed-f16 atomic message path (R8)
__device__ __forceinline__ float h2f(u16 u){ __half h; *reinterpret_cast<u16*>(&h)=u; return (float)h; }
__device__ __forceinline__ u32 f2h2pack(float lo, float hi){
  __half2 h2 = __floats2half2_rn(lo, hi);
  return *reinterpret_cast<u32*>(&h2);
}
__device__ __forceinline__ void atomic_pk_add_f16(u16* addr, u32 data){
  asm volatile("global_atomic_pk_add_f16 %0, %1, off" :: "v"(addr), "v"(data) : "memory");
}

template<int FP32> struct IO;
template<> struct IO<0> {
  static __device__ __forceinline__ float ld(const void* p, int i){ return bf2f(((const u16*)p)[i]); }
  static __device__ __forceinline__ void ld8(const void* p, int i, float* f){
    cvt8(*(const uint4*)((const u16*)p + i), f);
  }
  static __device__ __forceinline__ void st(void* p, int i, float v){ ((u16*)p)[i] = f2bf(v); }
};
template<> struct IO<1> {
  static __device__ __forceinline__ float ld(const void* p, int i){ return ((const float*)p)[i]; }
  static __device__ __forceinline__ void ld8(const void* p, int i, float* f){
    f32x4 a = *(const f32x4*)((const float*)p + i);
    f32x4 b = *(const f32x4*)((const float*)p + i + 4);
    f[0]=a[0]; f[1]=a[1]; f[2]=a[2]; f[3]=a[3];
    f[4]=b[0]; f[5]=b[1]; f[6]=b[2]; f[7]=b[3];
  }
  static __device__ __forceinline__ void st(void* p, int i, float v){ ((float*)p)[i] = v; }
};

// bf16-pair atomic add via u32 CAS (fallback tier only)
__device__ __forceinline__ void atomic_add_bf16pair(u32* addr, float lo, float hi){
  u32 old = *addr, assumed;
  do {
    assumed = old;
    float flo = bf2f((u16)(assumed & 0xFFFFu)) + lo;
    float fhi = bf2f((u16)(assumed >> 16)) + hi;
    u32 newv = (u32)f2bf(flo) | ((u32)f2bf(fhi) << 16);
    if (newv == assumed) return;
    old = atomicCAS(addr, assumed, newv);
  } while (old != assumed);
}

// ---------------- dtype probe (proven R4) ----------------
__global__ void k_probe(const u16* __restrict__ hraw, int* __restrict__ flag){
  if (threadIdx.x==0 && blockIdx.x==0){
    float mx = 0.f; int zc = 0;
    for (int i = 0; i < 256; i += 2){
      u16 u = hraw[i];
      if (u == 0) zc++;
      float v = fabsf(bf2f(u));
      mx = fmaxf(mx, v);
    }
    flag[0] = (mx > 1e3f || zc > 32) ? 1 : 0;
  }
}

// ---------------- CSR sort by dst (R9, dtype-independent) ----------------
__global__ __launch_bounds__(256) void k_hist(const int* __restrict__ eidx, int* __restrict__ cnt){
  int e = blockIdx.x*256 + threadIdx.x;
  if (e < EE) atomicAdd(&cnt[eidx[EE+e]], 1);
}
__global__ __launch_bounds__(1024) void k_scanA(const int* __restrict__ cnt,
                                               int* __restrict__ rowoff, int* __restrict__ bsum){
  __shared__ int s[1024];
  int t = threadIdx.x, b = blockIdx.x, i = b*1024 + t;
  int v = (i < NN) ? cnt[i] : 0;
  s[t] = v; __syncthreads();
  #pragma unroll
  for (int off=1; off<1024; off<<=1){
    int add = (t>=off) ? s[t-off] : 0;
    __syncthreads();
    s[t] += add;
    __syncthreads();
  }
  rowoff[i+1] = s[t];              // inclusive chunk scan, pre-offset
  if (t==1023) bsum[b] = s[t];
}
__global__ void k_scanB(int* __restrict__ bsum){
  if (threadIdx.x==0 && blockIdx.x==0){
    int acc=0;
    for (int b=0;b<SCAN_B;b++){ int v=bsum[b]; bsum[b]=acc; acc+=v; }
  }
}
__global__ __launch_bounds__(1024) void k_scanC(int* __restrict__ rowoff, int* __restrict__ cur,
                                               const int* __restrict__ bsum){
  int t = threadIdx.x, b = blockIdx.x, i = b*1024 + t;
  int v = rowoff[i+1] + bsum[b];
  rowoff[i+1] = v;
  if (i < NN-1) cur[i+1] = v;
  if (i==0){ rowoff[0]=0; cur[0]=0; }
}
__global__ __launch_bounds__(256) void k_scatter(const int* __restrict__ eidx,
                                                 int* __restrict__ cur, int* __restrict__ perm){
  int e = blockIdx.x*256 + threadIdx.x;
  if (e < EE){
    int p = atomicAdd(&cur[eidx[EE+e]], 1);
    perm[p] = e;
  }
}
// R12: pack (src,dst) per sorted edge (both < 65536). Removes one random-gather
// dependency level from k_edgeA's phase A. Dtype-independent.
__global__ __launch_bounds__(256) void k_permea(const int* __restrict__ eidx,
                                               const int* __restrict__ perm,
                                               u32* __restrict__ epack){
  int p = blockIdx.x*256 + threadIdx.x;
  if (p < EE){
    int e = perm[p];
    epack[p] = (u32)eidx[e] | ((u32)eidx[EE+e] << 16);
  }
}

// ---------------- weight pack (output always bf16) ----------------
template<int FP32>
__global__ __launch_bounds__(256) void k_prep(
    const int* __restrict__ flag,
    const void* __restrict__ We1, const void* __restrict__ We2,
    const void* __restrict__ Wx1, const void* __restrict__ Wh1,
    const void* __restrict__ Wh2,
    u16* __restrict__ WprojT, u16* __restrict__ We2T, u16* __restrict__ Wx1T,
    u16* __restrict__ Wh1T, u16* __restrict__ Wh2T, u16* __restrict__ Wrk9T)
{
  if (flag[0] != FP32) return;
  int i = blockIdx.x*256 + threadIdx.x;
  if (i < 49152){
    int n = i/192, k = i%192; float v;
    if (n < 128) v = (k<128) ? IO<FP32>::ld(We1, k*128+n) : IO<FP32>::ld(We1, (265+k-128)*128+n);
    else         v = (k<128) ? IO<FP32>::ld(We1, (128+k)*128+(n-128)) : 0.f;
    WprojT[i] = f2bf(v);
  } else if (i < 65536){
    int j=i-49152; int n=j/128, k=j%128; We2T[j] = f2bf(IO<FP32>::ld(We2, k*128+n));
  } else if (i < 81920){
    int j=i-65536; int n=j/128, k=j%128; Wx1T[j] = f2bf(IO<FP32>::ld(Wx1, k*128+n));
  } else if (i < 114688){
    int j=i-81920; int n=j/256, k=j%256; Wh1T[j] = f2bf(IO<FP32>::ld(Wh1, k*128+n));
  } else if (i < 131072){
    int j=i-114688; int n=j/128, k=j%128; Wh2T[j] = f2bf(IO<FP32>::ld(Wh2, k*128+n));
  } else if (i < 135168){
    int j=i-131072; int n=j/32, k=j%32;
    float v = (k<=8) ? IO<FP32>::ld(We1, (256+k)*128+n) : 0.f;
    Wrk9T[j] = f2bf(v);
  }
}

// ---------------- P13 (+P2 if WP2) ----------------
template<int FP32, int WP2>
__global__ __launch_bounds__(256) void k_proj(
    const int* __restrict__ flag,
    const void* __restrict__ h, const void* __restrict__ temb,
    const u16* __restrict__ WprojT, const void* __restrict__ We1b,
    u16* __restrict__ P13, u16* __restrict__ P2)
{
  if (flag[0] != FP32) return;
  constexpr int NT = WP2 ? 16 : 8;
  __shared__ __align__(16) u16 s_a[64][200];
  int tid = threadIdx.x; int nbase = blockIdx.x*64;
  {
    u32* p = (u32*)&s_a[0][0];
    for (int i = tid; i < 6400; i += 256) p[i] = 0u;
  }
  __syncthreads();
  {
    int r = tid>>2, p = tid&3; int node = nbase + r;
    if (node < NN){
      #pragma unroll
      for (int c=0;c<6;c++){
        int col = p*48 + c*8;
        float f[8];
        if (col<128) IO<FP32>::ld8(h, node*128 + col, f);
        else         IO<FP32>::ld8(temb, node*64 + (col-128), f);
        *(uint4*)&s_a[r][col] = pack8(f);
      }
    }
  }
  __syncthreads();
  int lane=tid&63, wid=tid>>6, quad=lane>>4, l15=lane&15, mb=wid*16;
  f32x4 acc[NT];
  #pragma unroll
  for (int nt=0;nt<NT;nt++) acc[nt]=(f32x4){0.f,0.f,0.f,0.f};
  #pragma unroll
  for (int ks=0;ks<6;ks++){
    short8 af = *(const short8*)&s_a[mb+l15][ks*32+quad*8];
    #pragma unroll
    for (int nt=0;nt<NT;nt++){
      short8 bfr = *(const short8*)(WprojT + (nt*16+l15)*192 + ks*32+quad*8);
      acc[nt] = __builtin_amdgcn_mfma_f32_16x16x32_bf16(af, bfr, acc[nt], 0,0,0);
    }
  }
  #pragma unroll
  for (int r=0;r<4;r++){
    int node = nbase + mb + quad*4 + r;
    if (node < NN){
      #pragma unroll
      for (int nt=0;nt<NT;nt++){
        int colg = nt*16 + l15;
        float v = acc[nt][r];
        if (colg < 128) P13[node*128+colg] = f2bf(v + IO<FP32>::ld(We1b, colg));
        else if (WP2)   P2[node*128+(colg-128)] = f2bf(v);
      }
    }
  }
}

// ---------------- fused edge kernel, tier A (R12): 128 edges/block, 32 edges/wave, 4 blocks/CU ----
// R12: epack removes eidx-gather level (all gathers at one dependent level);
//      final msg emit per tile deferred past GEMM2 weight loads (breaks vmcnt transitivity).
template<int FP32>
__global__ __launch_bounds__(256, 4) void k_edgeA(
    const int* __restrict__ flag,
    const void* __restrict__ x, const void* __restrict__ ea,
    const void* __restrict__ We2b, const void* __restrict__ Watt, const void* __restrict__ Wattb,
    const void* __restrict__ Wx1b, const void* __restrict__ Wx2, const void* __restrict__ Wx2b,
    const int* __restrict__ perm, const u32* __restrict__ epack,
    const u16* __restrict__ P13, const u16* __restrict__ P2,
    const u16* __restrict__ Wrk9T, const u16* __restrict__ We2T, const u16* __restrict__ Wx1T,
    u16* __restrict__ msgh, float* __restrict__ cagg)
{
  if (flag[0] != FP32) return;
  __shared__ int s_dst[128];
  __shared__ __align__(16) u16 s_hid[128][136];
  __shared__ __align__(16) u16 s_att[128][16];   // rank-9 A operand, k=0..15 (k9..15 zero)
  int tid = threadIdx.x;
  int ebase = blockIdx.x*128;
  float d0, d1, d2;   // dif kept in registers (all lanes), shfl'd in coord epilogue
  // ---- phase A: el = tid>>1, p = tid&1. epack gives src/dst at level 0; all gathers level 1.
  {
    int el = tid>>1, p = tid&1;
    u32 pk = epack[ebase+el];
    int srcI = (int)(pk & 0xFFFFu), dstI = (int)(pk >> 16);
    int e = perm[ebase+el];
    d0 = IO<FP32>::ld(x, srcI*3+0) - IO<FP32>::ld(x, dstI*3+0);
    d1 = IO<FP32>::ld(x, srcI*3+1) - IO<FP32>::ld(x, dstI*3+1);
    d2 = IO<FP32>::ld(x, srcI*3+2) - IO<FP32>::ld(x, dstI*3+2);
    float dsq = d0*d0 + d1*d1 + d2*d2;
    if (p==0){
      s_dst[el]=dstI;
      float eav[8]; IO<FP32>::ld8(ea, e*8, eav);
      float f9[8];
      f9[0]=dsq; for (int t=0;t<7;t++) f9[1+t]=eav[t];
      *(uint4*)&s_att[el][0] = pack8(f9);
      f9[0]=eav[7]; for (int t=1;t<8;t++) f9[t]=0.f;
      *(uint4*)&s_att[el][8] = pack8(f9);
    }
    const u16* p13r = P13 + srcI*128;
    const u16* p2r  = P2  + dstI*128;
    #pragma unroll
    for (int c=0;c<8;c++){
      int col = p*64 + c*8;
      float fa[8], fb[8];
      cvt8(*(const uint4*)(p13r+col), fa);
      cvt8(*(const uint4*)(p2r+col),  fb);
      #pragma unroll
      for (int i2=0;i2<8;i2++) fa[i2] += fb[i2];
      *(uint4*)&s_hid[el][col] = pack8(fa);
    }
  }
  int lane=tid&63, wid=tid>>6, quad=lane>>4, l15=lane&15;
  int rb = wid*32;
  // ---- rank-9 MFMA, both tiles share Wrk9T fragment loads; quads 2,3 feed zero A-fragments
  f32x4 acc9[2][8];
  #pragma unroll
  for (int t=0;t<2;t++)
    #pragma unroll
    for (int nt=0;nt<8;nt++) acc9[t][nt]=(f32x4){0.f,0.f,0.f,0.f};
  {
    short8 zf = (short8){0,0,0,0,0,0,0,0};
    short8 a90 = zf, a91 = zf;
    if (quad < 2){
      a90 = *(const short8*)&s_att[rb+l15][quad*8];
      a91 = *(const short8*)&s_att[rb+16+l15][quad*8];
    }
    #pragma unroll
    for (int nt=0;nt<8;nt++){
      short8 bfr = *(const short8*)(Wrk9T + (nt*16+l15)*32 + quad*8);
      acc9[0][nt] = __builtin_amdgcn_mfma_f32_16x16x32_bf16(a90, bfr, acc9[0][nt], 0,0,0);
      acc9[1][nt] = __builtin_amdgcn_mfma_f32_16x16x32_bf16(a91, bfr, acc9[1][nt], 0,0,0);
    }
  }
  // ---- fold + silu, both tiles
  #pragma unroll
  for (int t=0;t<2;t++){
    #pragma unroll
    for (int r=0;r<4;r++){
      int row = rb + t*16 + quad*4 + r;
      #pragma unroll
      for (int nt=0;nt<8;nt++){
        int col = nt*16+l15;
        float u = bf2f(s_hid[row][col]) + acc9[t][nt][r];
        u = u*sigmoidf_(u);
        s_hid[row][col] = f2bf(u);
      }
    }
  }
  // ---- GEMM1: m_pre = hid @ We2, tiles share weight loads, ks rolled
  f32x4 acc[2][8];
  #pragma unroll
  for (int t=0;t<2;t++)
    #pragma unroll
    for (int nt=0;nt<8;nt++) acc[t][nt]=(f32x4){0.f,0.f,0.f,0.f};
  #pragma unroll 1
  for (int ks=0;ks<4;ks++){
    short8 af0 = *(const short8*)&s_hid[rb+l15][ks*32+quad*8];
    short8 af1 = *(const short8*)&s_hid[rb+16+l15][ks*32+quad*8];
    #pragma unroll
    for (int nt=0;nt<8;nt++){
      short8 bfr = *(const short8*)(We2T + (nt*16+l15)*128 + ks*32+quad*8);
      acc[0][nt] = __builtin_amdgcn_mfma_f32_16x16x32_bf16(af0, bfr, acc[0][nt], 0,0,0);
      acc[1][nt] = __builtin_amdgcn_mfma_f32_16x16x32_bf16(af1, bfr, acc[1][nt], 0,0,0);
    }
  }
  // ---- epilogue per tile: attention gate, m -> s_hid overlay; boundary emits inline,
  //      final (r==3) emit deferred past GEMM2 (R12).
  float b2v[8], wav[8];
  #pragma unroll
  for (int nt=0;nt<8;nt++){ b2v[nt]=IO<FP32>::ld(We2b, nt*16+l15); wav[nt]=IO<FP32>::ld(Watt, nt*16+l15); }
  float attb = IO<FP32>::ld(Wattb, 0);
  float rfin[2][8]; int dstf[2];
  #pragma unroll
  for (int t=0;t<2;t++){
    float mval[8][4]; float dotr[4];
    #pragma unroll
    for (int r=0;r<4;r++){
      float s=0.f;
      #pragma unroll
      for (int nt=0;nt<8;nt++){ mval[nt][r]=acc[t][nt][r]+b2v[nt]; s += mval[nt][r]*wav[nt]; }
      dotr[r]=s;
    }
    #pragma unroll
    for (int off=1;off<16;off<<=1){
      #pragma unroll
      for (int r=0;r<4;r++) dotr[r] += __shfl_xor(dotr[r], off);
    }
    float racc[8];
    #pragma unroll
    for (int nt=0;nt<8;nt++) racc[nt]=0.f;
    #pragma unroll
    for (int r=0;r<4;r++){
      float att = sigmoidf_(dotr[r]+attb);
      int erow = rb + t*16 + quad*4 + r;
      int dstN = s_dst[erow];
      #pragma unroll
      for (int nt=0;nt<8;nt++){
        float v = mval[nt][r]*att;
        s_hid[erow][nt*16+l15] = f2bf(v);
        racc[nt] += v;
      }
      if (r < 3){
        bool boundary = (s_dst[erow+1] != dstN);
        #pragma unroll
        for (int nt=0;nt<8;nt++){
          float part = __shfl_xor(racc[nt], 1);
          if (boundary && ((l15 & 1) == 0)){
            atomic_pk_add_f16(msgh + dstN*128 + nt*16 + l15, f2h2pack(racc[nt], part));
          }
        }
        if (boundary){
          #pragma unroll
          for (int nt=0;nt<8;nt++) racc[nt]=0.f;
        }
      }
    }
    #pragma unroll
    for (int nt=0;nt<8;nt++) rfin[t][nt] = racc[nt];
    dstf[t] = s_dst[rb + t*16 + quad*4 + 3];
  }
  // ---- GEMM2: ch_pre = m @ Wx1, tiles share weight loads, ks rolled
  f32x4 acc2[2][8];
  #pragma unroll
  for (int t=0;t<2;t++)
    #pragma unroll
    for (int nt=0;nt<8;nt++) acc2[t][nt]=(f32x4){0.f,0.f,0.f,0.f};
  #pragma unroll 1
  for (int ks=0;ks<4;ks++){
    short8 af0 = *(const short8*)&s_hid[rb+l15][ks*32+quad*8];
    short8 af1 = *(const short8*)&s_hid[rb+16+l15][ks*32+quad*8];
    #pragma unroll
    for (int nt=0;nt<8;nt++){
      short8 bfr = *(const short8*)(Wx1T + (nt*16+l15)*128 + ks*32+quad*8);
      acc2[0][nt] = __builtin_amdgcn_mfma_f32_16x16x32_bf16(af0, bfr, acc2[0][nt], 0,0,0);
      acc2[1][nt] = __builtin_amdgcn_mfma_f32_16x16x32_bf16(af1, bfr, acc2[1][nt], 0,0,0);
    }
  }
  // ---- coord bias loads issued BEFORE deferred atomics (so their vmcnt wait excludes them)
  float bx1v[8], wx2v[8];
  #pragma unroll
  for (int nt=0;nt<8;nt++){ bx1v[nt]=IO<FP32>::ld(Wx1b, nt*16+l15); wx2v[nt]=IO<FP32>::ld(Wx2, nt*16+l15); }
  float bx2f = IO<FP32>::ld(Wx2b, 0);
  // ---- deferred final msg emits (both tiles)
  #pragma unroll
  for (int t=0;t<2;t++){
    #pragma unroll
    for (int nt=0;nt<8;nt++){
      float part = __shfl_xor(rfin[t][nt], 1);
      if ((l15 & 1) == 0){
        atomic_pk_add_f16(msgh + dstf[t]*128 + nt*16 + l15, f2h2pack(rfin[t][nt], part));
      }
    }
  }
  // ---- coord epilogue per tile: dif via shfl from phase-A registers; run-compressed fp32 atomics
  #pragma unroll
  for (int t=0;t<2;t++){
    float dc[4];
    #pragma unroll
    for (int r=0;r<4;r++){
      float s=0.f;
      #pragma unroll
      for (int nt=0;nt<8;nt++){
        float u = acc2[t][nt][r] + bx1v[nt];
        u = u*sigmoidf_(u);
        s += u*wx2v[nt];
      }
      dc[r]=s;
    }
    #pragma unroll
    for (int off=1;off<16;off<<=1){
      #pragma unroll
      for (int r=0;r<4;r++) dc[r] += __shfl_xor(dc[r], off);
    }
    float c0=0.f, c1=0.f, c2=0.f;
    #pragma unroll
    for (int r=0;r<4;r++){
      float cw = tanhf(dc[r]+bx2f);
      int eloc = t*16 + quad*4 + r;          // wave-local edge row
      int erow = rb + eloc;
      int srcL = 2*eloc;                     // phase-A writer lane for this edge
      float e0 = __shfl(d0, srcL);
      float e1 = __shfl(d1, srcL);
      float e2 = __shfl(d2, srcL);
      c0 += e0*cw; c1 += e1*cw; c2 += e2*cw;
      int dstN = s_dst[erow];
      bool emit = (r==3) || (s_dst[erow+1] != dstN);
      if (emit){
        if (l15==0){
          atomicAdd(&cagg[dstN*4+0], c0);
          atomicAdd(&cagg[dstN*4+1], c1);
          atomicAdd(&cagg[dstN*4+2], c2);
        }
        c0=0.f; c1=0.f; c2=0.f;
      }
    }
  }
}

// ---------------- fused edge kernel, fallback tier (R5/R6-proven, 64 edges/block) ----------------
template<int FP32>
__global__ __launch_bounds__(256, 6) void k_edgeB(
    const int* __restrict__ flag,
    const void* __restrict__ x, const void* __restrict__ ea,
    const void* __restrict__ We1, const void* __restrict__ h,
    const void* __restrict__ We2b, const void* __restrict__ Watt, const void* __restrict__ Wattb,
    const void* __restrict__ Wx1b, const void* __restrict__ Wx2, const void* __restrict__ Wx2b,
    const int* __restrict__ eidx,
    const u16* __restrict__ P13,
    const u16* __restrict__ WprojT,
    const u16* __restrict__ We2T, const u16* __restrict__ Wx1T,
    u16* __restrict__ msgb, float* __restrict__ cagg)
{
  if (flag[0] != FP32) return;
  __shared__ int s_dst[64];
  __shared__ float s_dif[64][3];
  __shared__ __align__(16) u16 s_hid[64][136];
  __shared__ __align__(16) u16 s_m[64][136];
  __shared__ __align__(16) u16 s_hd[64][136];
  int tid = threadIdx.x;
  int ebase = blockIdx.x*64;
  {
    int el = tid>>2, p = tid&3;
    int e = ebase+el;
    int srcI = eidx[e], dstI = eidx[EE+e];
    float d0 = IO<FP32>::ld(x, srcI*3+0) - IO<FP32>::ld(x, dstI*3+0);
    float d1 = IO<FP32>::ld(x, srcI*3+1) - IO<FP32>::ld(x, dstI*3+1);
    float d2 = IO<FP32>::ld(x, srcI*3+2) - IO<FP32>::ld(x, dstI*3+2);
    float dsq = d0*d0 + d1*d1 + d2*d2;
    if (p==0){ s_dst[el]=dstI; s_dif[el][0]=d0; s_dif[el][1]=d1; s_dif[el][2]=d2; }
    float eav[8]; IO<FP32>::ld8(ea, e*8, eav);
    const u16* p13r = P13 + srcI*128;
    #pragma unroll
    for (int c=0;c<4;c++){
      int col = p*32 + c*8;
      float fw[8], pre[8];
      cvt8(*(const uint4*)(p13r+col), pre);
      IO<FP32>::ld8(We1, 256*128 + col, fw);
      #pragma unroll
      for (int i2=0;i2<8;i2++) pre[i2] += dsq*fw[i2];
      #pragma unroll
      for (int t=0;t<8;t++){
        IO<FP32>::ld8(We1, (257+t)*128 + col, fw);
        #pragma unroll
        for (int i2=0;i2<8;i2++) pre[i2] += eav[t]*fw[i2];
      }
      *(uint4*)&s_hid[el][col] = pack8(pre);
      float hd[8]; IO<FP32>::ld8(h, dstI*128 + col, hd);
      *(uint4*)&s_hd[el][col] = pack8(hd);
    }
  }
  int lane=tid&63, wid=tid>>6, quad=lane>>4, l15=lane&15, mb=wid*16;
  {
    f32x4 accg[8];
    #pragma unroll
    for (int nt=0;nt<8;nt++) accg[nt]=(f32x4){0.f,0.f,0.f,0.f};
    #pragma unroll
    for (int ks=0;ks<4;ks++){
      short8 af = *(const short8*)&s_hd[mb+l15][ks*32+quad*8];
      #pragma unroll
      for (int nt=0;nt<8;nt++){
        short8 bfr = *(const short8*)(WprojT + (128 + nt*16+l15)*192 + ks*32+quad*8);
        accg[nt] = __builtin_amdgcn_mfma_f32_16x16x32_bf16(af, bfr, accg[nt], 0,0,0);
      }
    }
    #pragma unroll
    for (int r=0;r<4;r++){
      int row = mb + quad*4 + r;
      #pragma unroll
      for (int nt=0;nt<8;nt++){
        int col = nt*16+l15;
        float u = bf2f(s_hid[row][col]) + accg[nt][r];
        u = u*sigmoidf_(u);
        s_hid[row][col] = f2bf(u);
      }
    }
  }
  f32x4 acc[8];
  #pragma unroll
  for (int nt=0;nt<8;nt++) acc[nt]=(f32x4){0.f,0.f,0.f,0.f};
  #pragma unroll
  for (int ks=0;ks<4;ks++){
    short8 af = *(const short8*)&s_hid[mb+l15][ks*32+quad*8];
    #pragma unroll
    for (int nt=0;nt<8;nt++){
      short8 bfr = *(const short8*)(We2T + (nt*16+l15)*128 + ks*32+quad*8);
      acc[nt] = __builtin_amdgcn_mfma_f32_16x16x32_bf16(af, bfr, acc[nt], 0,0,0);
    }
  }
  float b2v[8], wav[8];
  #pragma unroll
  for (int nt=0;nt<8;nt++){ b2v[nt]=IO<FP32>::ld(We2b, nt*16+l15); wav[nt]=IO<FP32>::ld(Watt, nt*16+l15); }
  float attb = IO<FP32>::ld(Wattb, 0);
  float mval[8][4]; float dotr[4];
  #pragma unroll
  for (int r=0;r<4;r++){
    float s=0.f;
    #pragma unroll
    for (int nt=0;nt<8;nt++){ mval[nt][r]=acc[nt][r]+b2v[nt]; s += mval[nt][r]*wav[nt]; }
    dotr[r]=s;
  }
  #pragma unroll
  for (int off=1;off<16;off<<=1){
    #pragma unroll
    for (int r=0;r<4;r++) dotr[r] += __shfl_xor(dotr[r], off);
  }
  #pragma unroll
  for (int r=0;r<4;r++){
    float att = sigmoidf_(dotr[r]+attb);
    int erow = mb + quad*4 + r;
    int dstN = s_dst[erow];
    #pragma unroll
    for (int nt=0;nt<8;nt++){
      float v = mval[nt][r]*att;
      mval[nt][r] = v;
      s_m[erow][nt*16+l15] = f2bf(v);
    }
    #pragma unroll
    for (int nt=0;nt<8;nt++){
      float part = __shfl_xor(mval[nt][r], 1);
      if ((l15 & 1) == 0){
        atomic_add_bf16pair((u32*)(msgb + dstN*128 + nt*16 + l15), mval[nt][r], part);
      }
    }
  }
  f32x4 acc2[8];
  #pragma unroll
  for (int nt=0;nt<8;nt++) acc2[nt]=(f32x4){0.f,0.f,0.f,0.f};
  #pragma unroll
  for (int ks=0;ks<4;ks++){
    short8 af = *(const short8*)&s_m[mb+l15][ks*32+quad*8];
    #pragma unroll
    for (int nt=0;nt<8;nt++){
      short8 bfr = *(const short8*)(Wx1T + (nt*16+l15)*128 + ks*32+quad*8);
      acc2[nt] = __builtin_amdgcn_mfma_f32_16x16x32_bf16(af, bfr, acc2[nt], 0,0,0);
    }
  }
  float bx1v[8], wx2v[8];
  #pragma unroll
  for (int nt=0;nt<8;nt++){ bx1v[nt]=IO<FP32>::ld(Wx1b, nt*16+l15); wx2v[nt]=IO<FP32>::ld(Wx2, nt*16+l15); }
  float bx2f = IO<FP32>::ld(Wx2b, 0);
  float dc[4];
  #pragma unroll
  for (int r=0;r<4;r++){
    float s=0.f;
    #pragma unroll
    for (int nt=0;nt<8;nt++){
      float u = acc2[nt][r] + bx1v[nt];
      u = u*sigmoidf_(u);
      s += u*wx2v[nt];
    }
    dc[r]=s;
  }
  #pragma unroll
  for (int off=1;off<16;off<<=1){
    #pragma unroll
    for (int r=0;r<4;r++) dc[r] += __shfl_xor(dc[r], off);
  }
  #pragma unroll
  for (int r=0;r<4;r++){
    float cw = tanhf(dc[r]+bx2f);
    if (l15==0){
      int erow = mb + quad*4 + r;
      int dstN = s_dst[erow];
      atomicAdd(&cagg[dstN*4+0], s_dif[erow][0]*cw);
      atomicAdd(&cagg[dstN*4+1], s_dif[erow][1]*cw);
      atomicAdd(&cagg[dstN*4+2], s_dif[erow][2]*cw);
      atomicAdd(&cagg[dstN*4+3], 1.0f);
    }
  }
}

// ---------------- node update ----------------
// MSGF=1: tierA — msg buffer is f16, deg from CSR rowoff. MSGF=0: fallback — bf16 msg, deg from cagg[3].
template<int FP32, int MSGF>
__global__ __launch_bounds__(256) void k_node(
    const int* __restrict__ flag,
    const void* __restrict__ h, const void* __restrict__ x,
    const u16* __restrict__ msgh, const u16* __restrict__ msgb,
    const float* __restrict__ cagg, const int* __restrict__ rowoff,
    const u16* __restrict__ Wh1T, const void* __restrict__ Wh1b,
    const u16* __restrict__ Wh2T, const void* __restrict__ Wh2b,
    void* __restrict__ out)
{
  if (flag[0] != FP32) return;
  __shared__ __align__(16) u16 s_a[64][264];
  __shared__ __align__(16) u16 s_u[64][136];
  int tid = threadIdx.x; int nbase = blockIdx.x*64;
  {
    u32* p1 = (u32*)&s_a[0][0];
    for (int i = tid; i < 8448; i += 256) p1[i] = 0u;
  }
  __syncthreads();
  {
    int r = tid>>2, p = tid&3; int node = nbase + r;
    if (node < NN){
      #pragma unroll
      for (int c=0;c<8;c++){
        int col = p*64 + c*8;
        if (col < 128){
          float f[8]; IO<FP32>::ld8(h, node*128 + col, f);
          *(uint4*)&s_a[r][col] = pack8(f);
        } else if (MSGF){
          uint4 q = *(const uint4*)(msgh + node*128 + (col-128));
          float f[8];
          f[0]=h2f((u16)(q.x&0xFFFF)); f[1]=h2f((u16)(q.x>>16));
          f[2]=h2f((u16)(q.y&0xFFFF)); f[3]=h2f((u16)(q.y>>16));
          f[4]=h2f((u16)(q.z&0xFFFF)); f[5]=h2f((u16)(q.z>>16));
          f[6]=h2f((u16)(q.w&0xFFFF)); f[7]=h2f((u16)(q.w>>16));
          *(uint4*)&s_a[r][col] = pack8(f);
        } else {
          *(uint4*)&s_a[r][col] = *(const uint4*)(msgb + node*128 + (col-128));
        }
      }
    }
  }
  __syncthreads();
  int lane=tid&63, wid=tid>>6, quad=lane>>4, l15=lane&15, mb=wid*16;
  f32x4 acc[8];
  #pragma unroll
  for (int nt=0;nt<8;nt++) acc[nt]=(f32x4){0.f,0.f,0.f,0.f};
  #pragma unroll
  for (int ks=0;ks<8;ks++){
    short8 af = *(const short8*)&s_a[mb+l15][ks*32+quad*8];
    #pragma unroll
    for (int nt=0;nt<8;nt++){
      short8 bfr = *(const short8*)(Wh1T + (nt*16+l15)*256 + ks*32+quad*8);
      acc[nt] = __builtin_amdgcn_mfma_f32_16x16x32_bf16(af, bfr, acc[nt], 0,0,0);
    }
  }
  #pragma unroll
  for (int r=0;r<4;r++){
    int row = mb + quad*4 + r;
    #pragma unroll
    for (int nt=0;nt<8;nt++){
      int col = nt*16+l15;
      float u = acc[nt][r] + IO<FP32>::ld(Wh1b, col);
      u = u*sigmoidf_(u);
      s_u[row][col] = f2bf(u);
    }
  }
  f32x4 acc2[8];
  #pragma unroll
  for (int nt=0;nt<8;nt++) acc2[nt]=(f32x4){0.f,0.f,0.f,0.f};
  #pragma unroll
  for (int ks=0;ks<4;ks++){
    short8 af = *(const short8*)&s_u[mb+l15][ks*32+quad*8];
    #pragma unroll
    for (int nt=0;nt<8;nt++){
      short8 bfr = *(const short8*)(Wh2T + (nt*16+l15)*128 + ks*32+quad*8);
      acc2[nt] = __builtin_amdgcn_mfma_f32_16x16x32_bf16(af, bfr, acc2[nt], 0,0,0);
    }
  }
  #pragma unroll
  for (int r=0;r<4;r++){
    int node = nbase + mb + quad*4 + r;
    if (node < NN){
      #pragma unroll
      for (int nt=0;nt<8;nt++){
        int col = nt*16+l15;
        float v = IO<FP32>::ld(h, node*128+col) + acc2[nt][r] + IO<FP32>::ld(Wh2b, col);
        IO<FP32>::st(out, node*128+col, v);
      }
    }
  }
  if (tid < 64){
    int node = nbase + tid;
    if (node < NN){
      float deg = MSGF ? (float)(rowoff[node+1]-rowoff[node]) : cagg[node*4+3];
      float inv = 1.0f/(deg + 1.0f);
      #pragma unroll
      for (int c=0;c<3;c++){
        float v = IO<FP32>::ld(x, node*3+c) + cagg[node*4+c]*inv;
        IO<FP32>::st(out, NN*128 + node*3 + c, v);
      }
    }
  }
}

extern "C" void kernel_launch(void* const* d_in, const int* in_sizes, int n_in,
                              void* d_out, int out_size, void* d_ws, size_t ws_size,
                              hipStream_t stream) {
  const void* h     = d_in[0];
  const void* x     = d_in[1];
  const void* ea    = d_in[2];
  const void* temb  = d_in[3];
  const void* We1   = d_in[4];
  const void* We1b  = d_in[5];
  const void* We2   = d_in[6];
  const void* We2b  = d_in[7];
  const void* Watt  = d_in[8];
  const void* Wattb = d_in[9];
  const void* Wx1   = d_in[10];
  const void* Wx1b  = d_in[11];
  const void* Wx2   = d_in[12];
  const void* Wx2b  = d_in[13];
  const void* Wh1   = d_in[14];
  const void* Wh1b  = d_in[15];
  const void* Wh2   = d_in[16];
  const void* Wh2b  = d_in[17];
  const int* eidx   = (const int*)d_in[18];
  char* ws = (char*)d_ws;

  u16* WprojT = (u16*)(ws + 0);          //  98,304
  u16* We2T   = (u16*)(ws + 98304);      //  32,768
  u16* Wx1T   = (u16*)(ws + 131072);     //  32,768
  u16* Wh1T   = (u16*)(ws + 163840);     //  65,536
  u16* Wh2T   = (u16*)(ws + 229376);     //  32,768  -> 262,144
  u16* Wrk9T  = (u16*)(ws + 262144);     //   8,192  -> 270,336
  float* cagg = (float*)(ws + 270336);   // 800,000  -> 1,070,336
  int* flag   = (int*)(ws + 1070336);    //     256  -> 1,070,592
  bool tierA = (ws_size >= (size_t)39470592);
  u16* msgh   = (u16*)(ws + 1070592);    // tierA: f16 [NN][128] = 12,800,000 -> 13,870,592
  u16* msgb   = (u16*)(ws + 1070592);    // fallback: bf16 [NN][128]
  u16* P2     = (u16*)(ws + 13870592);   // tierA: 12,800,000 -> 26,670,592
  int* cnt    = (int*)(ws + 26670592);   // 200,704 -> 26,871,296
  int* rowoff = (int*)(ws + 26871296);   // 201,216 -> 27,072,512
  int* cur    = (int*)(ws + 27072512);   // 200,704 -> 27,273,216
  int* bsum   = (int*)(ws + 27273216);   //     256 -> 27,273,472
  int* perm   = (int*)(ws + 27273472);   // 3,200,000 -> 30,473,472
  u32* epack  = (u32*)(ws + 30473472);   // 3,200,000 -> 33,673,472 (R12)
  u16* P13    = (u16*)d_out;

  // zero cagg + flag + msg buffer (13.6 MB)
  hipMemsetAsync(ws + 270336, 0, 13600256, stream);
  k_probe<<<1, 64, 0, stream>>>((const u16*)h, flag);
  if (tierA){
    // CSR sort by dst (dtype-independent)
    hipMemsetAsync(cnt, 0, 200704, stream);
    k_hist<<<(EE+255)/256, 256, 0, stream>>>(eidx, cnt);
    k_scanA<<<SCAN_B, 1024, 0, stream>>>(cnt, rowoff, bsum);
    k_scanB<<<1, 64, 0, stream>>>(bsum);
    k_scanC<<<SCAN_B, 1024, 0, stream>>>(rowoff, cur, bsum);
    k_scatter<<<(EE+255)/256, 256, 0, stream>>>(eidx, cur, perm);
    k_permea<<<(EE+255)/256, 256, 0, stream>>>(eidx, perm, epack);
  }
  k_prep<0><<<528, 256, 0, stream>>>(flag, We1, We2, Wx1, Wh1, Wh2, WprojT, We2T, Wx1T, Wh1T, Wh2T, Wrk9T);
  k_prep<1><<<528, 256, 0, stream>>>(flag, We1, We2, Wx1, Wh1, Wh2, WprojT, We2T, Wx1T, Wh1T, Wh2T, Wrk9T);
  if (tierA){
    k_proj<0,1><<<(NN+63)/64, 256, 0, stream>>>(flag, h, temb, WprojT, We1b, P13, P2);
    k_proj<1,1><<<(NN+63)/64, 256, 0, stream>>>(flag, h, temb, WprojT, We1b, P13, P2);
    k_edgeA<0><<<EE/128, 256, 0, stream>>>(flag, x, ea, We2b, Watt, Wattb, Wx1b, Wx2, Wx2b,
                                           perm, epack, P13, P2, Wrk9T, We2T, Wx1T, msgh, cagg);
    k_edgeA<1><<<EE/128, 256, 0, stream>>>(flag, x, ea, We2b, Watt, Wattb, Wx1b, Wx2, Wx2b,
                                           perm, epack, P13, P2, Wrk9T, We2T, Wx1T, msgh, cagg);
    k_node<0,1><<<(NN+63)/64, 256, 0, stream>>>(flag, h, x, msgh, msgb, cagg, rowoff, Wh1T, Wh1b, Wh2T, Wh2b, d_out);
    k_node<1,1><<<(NN+63)/64, 256, 0, stream>>>(flag, h, x, msgh, msgb, cagg, rowoff, Wh1T, Wh1b, Wh2T, Wh2b, d_out);
  } else {
    k_proj<0,0><<<(NN+63)/64, 256, 0, stream>>>(flag, h, temb, WprojT, We1b, P13, P2);
    k_proj<1,0><<<(NN+63)/64, 256, 0, stream>>>(flag, h, temb, WprojT, We1b, P13, P2);
    k_edgeB<0><<<EE/64, 256, 0, stream>>>(flag, x, ea, We1, h, We2b, Watt, Wattb, Wx1b, Wx2, Wx2b,
                                          eidx, P13, WprojT, We2T, Wx1T, msgb, cagg);
    k_edgeB<1><<<EE/64, 256, 0, stream>>>(flag, x, ea, We1, h, We2b, Watt, Wattb, Wx1b, Wx2, Wx2b,
                                          eidx, P13, WprojT, We2T, Wx1T, msgb, cagg);
    k_node<0,0><<<(NN+63)/64, 256, 0, stream>>>(flag, h, x, msgh, msgb, cagg, rowoff, Wh1T, Wh1b, Wh2T, Wh2b, d_out);
    k_node<1,0><<<(NN+63)/64, 256, 0, stream>>>(flag, h, x, msgh, msgb, cagg, rowoff, Wh1T, Wh1b, Wh2T, Wh2b, d_out);
  }
}

// Round 15
// 833.628 us; speedup vs baseline: 1.0180x; 1.0180x over previous
//
#include <hip/hip_runtime.h>
#include <hip/hip_fp16.h>

typedef unsigned short u16;
typedef unsigned int u32;
typedef __attribute__((ext_vector_type(8))) short short8;
typedef __attribute__((ext_vector_type(4))) float f32x4;

#define NN 50000
#define EE 800000
#define SCAN_B 49   // 49 blocks x 1024 = 50176 >= NN

__device__ __forceinline__ float bf2f(u16 u){ union{u32 i; float f;} v; v.i=((u32)u)<<16; return v.f; }
__device__ __forceinline__ u16 f2bf(float f){ union{float f; u32 i;} v; v.f=f; u32 b=v.i; b += 0x7FFFu + ((b>>16)&1u); return (u16)(b>>16); }
__device__ __forceinline__ float sigmoidf_(float x){ return 1.0f/(1.0f+__expf(-x)); }

__device__ __forceinline__ void cvt8(uint4 q, float* f){
  f[0]=bf2f((u16)(q.x&0xFFFF)); f[1]=bf2f((u16)(q.x>>16));
  f[2]=bf2f((u16)(q.y&0xFFFF)); f[3]=bf2f((u16)(q.y>>16));
  f[4]=bf2f((u16)(q.z&0xFFFF)); f[5]=bf2f((u16)(q.z>>16));
  f[6]=bf2f((u16)(q.w&0xFFFF)); f[7]=bf2f((u16)(q.w>>16));
}
// R11: hardware packed f32->bf16 convert (RNE, identical to f2bf rounding).
__device__ __forceinline__ u32 cvtpk_bf16(float lo, float hi){
  u32 r; asm("v_cvt_pk_bf16_f32 %0, %1, %2" : "=v"(r) : "v"(lo), "v"(hi)); return r;
}
__device__ __forceinline__ uint4 pack8(const float* f){
  uint4 q;
  q.x=cvtpk_bf16(f[0],f[1]);
  q.y=cvtpk_bf16(f[2],f[3]);
  q.z=cvtpk_bf16(f[4],f[5]);
  q.w=cvtpk_bf16(f[6],f[7]);
  return q;
}

// f16 helpers for the packed-f16 atomic message path (R8)
__device__ __forceinline__ float h2f(u16 u){ __half h; *reinterpret_cast<u16*>(&h)=u; return (float)h; }
__device__ __forceinline__ u32 f2h2pack(float lo, float hi){
  __half2 h2 = __floats2half2_rn(lo, hi);
  return *reinterpret_cast<u32*>(&h2);
}
__device__ __forceinline__ void atomic_pk_add_f16(u16* addr, u32 data){
  asm volatile("global_atomic_pk_add_f16 %0, %1, off" :: "v"(addr), "v"(data) : "memory");
}

template<int FP32> struct IO;
template<> struct IO<0> {
  static __device__ __forceinline__ float ld(const void* p, int i){ return bf2f(((const u16*)p)[i]); }
  static __device__ __forceinline__ void ld8(const void* p, int i, float* f){
    cvt8(*(const uint4*)((const u16*)p + i), f);
  }
  static __device__ __forceinline__ void st(void* p, int i, float v){ ((u16*)p)[i] = f2bf(v); }
};
template<> struct IO<1> {
  static __device__ __forceinline__ float ld(const void* p, int i){ return ((const float*)p)[i]; }
  static __device__ __forceinline__ void ld8(const void* p, int i, float* f){
    f32x4 a = *(const f32x4*)((const float*)p + i);
    f32x4 b = *(const f32x4*)((const float*)p + i + 4);
    f[0]=a[0]; f[1]=a[1]; f[2]=a[2]; f[3]=a[3];
    f[4]=b[0]; f[5]=b[1]; f[6]=b[2]; f[7]=b[3];
  }
  static __device__ __forceinline__ void st(void* p, int i, float v){ ((float*)p)[i] = v; }
};

// bf16-pair atomic add via u32 CAS (fallback tier only)
__device__ __forceinline__ void atomic_add_bf16pair(u32* addr, float lo, float hi){
  u32 old = *addr, assumed;
  do {
    assumed = old;
    float flo = bf2f((u16)(assumed & 0xFFFFu)) + lo;
    float fhi = bf2f((u16)(assumed >> 16)) + hi;
    u32 newv = (u32)f2bf(flo) | ((u32)f2bf(fhi) << 16);
    if (newv == assumed) return;
    old = atomicCAS(addr, assumed, newv);
  } while (old != assumed);
}

// ---------------- dtype probe (proven R4) ----------------
__global__ void k_probe(const u16* __restrict__ hraw, int* __restrict__ flag){
  if (threadIdx.x==0 && blockIdx.x==0){
    float mx = 0.f; int zc = 0;
    for (int i = 0; i < 256; i += 2){
      u16 u = hraw[i];
      if (u == 0) zc++;
      float v = fabsf(bf2f(u));
      mx = fmaxf(mx, v);
    }
    flag[0] = (mx > 1e3f || zc > 32) ? 1 : 0;
  }
}

// ---------------- CSR sort by dst (R9, dtype-independent) ----------------
__global__ __launch_bounds__(256) void k_hist(const int* __restrict__ eidx, int* __restrict__ cnt){
  int e = blockIdx.x*256 + threadIdx.x;
  if (e < EE) atomicAdd(&cnt[eidx[EE+e]], 1);
}
__global__ __launch_bounds__(1024) void k_scanA(const int* __restrict__ cnt,
                                               int* __restrict__ rowoff, int* __restrict__ bsum){
  __shared__ int s[1024];
  int t = threadIdx.x, b = blockIdx.x, i = b*1024 + t;
  int v = (i < NN) ? cnt[i] : 0;
  s[t] = v; __syncthreads();
  #pragma unroll
  for (int off=1; off<1024; off<<=1){
    int add = (t>=off) ? s[t-off] : 0;
    __syncthreads();
    s[t] += add;
    __syncthreads();
  }
  rowoff[i+1] = s[t];              // inclusive chunk scan, pre-offset
  if (t==1023) bsum[b] = s[t];
}
__global__ void k_scanB(int* __restrict__ bsum){
  if (threadIdx.x==0 && blockIdx.x==0){
    int acc=0;
    for (int b=0;b<SCAN_B;b++){ int v=bsum[b]; bsum[b]=acc; acc+=v; }
  }
}
__global__ __launch_bounds__(1024) void k_scanC(int* __restrict__ rowoff, int* __restrict__ cur,
                                               const int* __restrict__ bsum){
  int t = threadIdx.x, b = blockIdx.x, i = b*1024 + t;
  int v = rowoff[i+1] + bsum[b];
  rowoff[i+1] = v;
  if (i < NN-1) cur[i+1] = v;
  if (i==0){ rowoff[0]=0; cur[0]=0; }
}
__global__ __launch_bounds__(256) void k_scatter(const int* __restrict__ eidx,
                                                 int* __restrict__ cur, int* __restrict__ perm){
  int e = blockIdx.x*256 + threadIdx.x;
  if (e < EE){
    int p = atomicAdd(&cur[eidx[EE+e]], 1);
    perm[p] = e;
  }
}
// R12: pack (src,dst) per sorted edge (both < 65536). Removes one random-gather
// dependency level from k_edgeA's phase A. Dtype-independent.
__global__ __launch_bounds__(256) void k_permea(const int* __restrict__ eidx,
                                               const int* __restrict__ perm,
                                               u32* __restrict__ epack){
  int p = blockIdx.x*256 + threadIdx.x;
  if (p < EE){
    int e = perm[p];
    epack[p] = (u32)eidx[e] | ((u32)eidx[EE+e] << 16);
  }
}

// ---------------- weight pack (output always bf16) ----------------
template<int FP32>
__global__ __launch_bounds__(256) void k_prep(
    const int* __restrict__ flag,
    const void* __restrict__ We1, const void* __restrict__ We2,
    const void* __restrict__ Wx1, const void* __restrict__ Wh1,
    const void* __restrict__ Wh2,
    u16* __restrict__ WprojT, u16* __restrict__ We2T, u16* __restrict__ Wx1T,
    u16* __restrict__ Wh1T, u16* __restrict__ Wh2T, u16* __restrict__ Wrk9T)
{
  if (flag[0] != FP32) return;
  int i = blockIdx.x*256 + threadIdx.x;
  if (i < 49152){
    int n = i/192, k = i%192; float v;
    if (n < 128) v = (k<128) ? IO<FP32>::ld(We1, k*128+n) : IO<FP32>::ld(We1, (265+k-128)*128+n);
    else         v = (k<128) ? IO<FP32>::ld(We1, (128+k)*128+(n-128)) : 0.f;
    WprojT[i] = f2bf(v);
  } else if (i < 65536){
    int j=i-49152; int n=j/128, k=j%128; We2T[j] = f2bf(IO<FP32>::ld(We2, k*128+n));
  } else if (i < 81920){
    int j=i-65536; int n=j/128, k=j%128; Wx1T[j] = f2bf(IO<FP32>::ld(Wx1, k*128+n));
  } else if (i < 114688){
    int j=i-81920; int n=j/256, k=j%256; Wh1T[j] = f2bf(IO<FP32>::ld(Wh1, k*128+n));
  } else if (i < 131072){
    int j=i-114688; int n=j/128, k=j%128; Wh2T[j] = f2bf(IO<FP32>::ld(Wh2, k*128+n));
  } else if (i < 135168){
    int j=i-131072; int n=j/32, k=j%32;
    float v = (k<=8) ? IO<FP32>::ld(We1, (256+k)*128+n) : 0.f;
    Wrk9T[j] = f2bf(v);
  }
}

// ---------------- P13 (+P2 if WP2) ----------------
template<int FP32, int WP2>
__global__ __launch_bounds__(256) void k_proj(
    const int* __restrict__ flag,
    const void* __restrict__ h, const void* __restrict__ temb,
    const u16* __restrict__ WprojT, const void* __restrict__ We1b,
    u16* __restrict__ P13, u16* __restrict__ P2)
{
  if (flag[0] != FP32) return;
  constexpr int NT = WP2 ? 16 : 8;
  __shared__ __align__(16) u16 s_a[64][200];
  int tid = threadIdx.x; int nbase = blockIdx.x*64;
  {
    u32* p = (u32*)&s_a[0][0];
    for (int i = tid; i < 6400; i += 256) p[i] = 0u;
  }
  __syncthreads();
  {
    int r = tid>>2, p = tid&3; int node = nbase + r;
    if (node < NN){
      #pragma unroll
      for (int c=0;c<6;c++){
        int col = p*48 + c*8;
        float f[8];
        if (col<128) IO<FP32>::ld8(h, node*128 + col, f);
        else         IO<FP32>::ld8(temb, node*64 + (col-128), f);
        *(uint4*)&s_a[r][col] = pack8(f);
      }
    }
  }
  __syncthreads();
  int lane=tid&63, wid=tid>>6, quad=lane>>4, l15=lane&15, mb=wid*16;
  f32x4 acc[NT];
  #pragma unroll
  for (int nt=0;nt<NT;nt++) acc[nt]=(f32x4){0.f,0.f,0.f,0.f};
  #pragma unroll
  for (int ks=0;ks<6;ks++){
    short8 af = *(const short8*)&s_a[mb+l15][ks*32+quad*8];
    #pragma unroll
    for (int nt=0;nt<NT;nt++){
      short8 bfr = *(const short8*)(WprojT + (nt*16+l15)*192 + ks*32+quad*8);
      acc[nt] = __builtin_amdgcn_mfma_f32_16x16x32_bf16(af, bfr, acc[nt], 0,0,0);
    }
  }
  #pragma unroll
  for (int r=0;r<4;r++){
    int node = nbase + mb + quad*4 + r;
    if (node < NN){
      #pragma unroll
      for (int nt=0;nt<NT;nt++){
        int colg = nt*16 + l15;
        float v = acc[nt][r];
        if (colg < 128) P13[node*128+colg] = f2bf(v + IO<FP32>::ld(We1b, colg));
        else if (WP2)   P2[node*128+(colg-128)] = f2bf(v);
      }
    }
  }
}

// ---------------- fused edge kernel, tier A (R13): 128 edges/block, 32 edges/wave, 4 blocks/CU ----
// R13 = R11 k_edgeA + epack phase-A only (R12's deferred emit reverted — it regressed).
template<int FP32>
__global__ __launch_bounds__(256, 4) void k_edgeA(
    const int* __restrict__ flag,
    const void* __restrict__ x, const void* __restrict__ ea,
    const void* __restrict__ We2b, const void* __restrict__ Watt, const void* __restrict__ Wattb,
    const void* __restrict__ Wx1b, const void* __restrict__ Wx2, const void* __restrict__ Wx2b,
    const int* __restrict__ perm, const u32* __restrict__ epack,
    const u16* __restrict__ P13, const u16* __restrict__ P2,
    const u16* __restrict__ Wrk9T, const u16* __restrict__ We2T, const u16* __restrict__ Wx1T,
    u16* __restrict__ msgh, float* __restrict__ cagg)
{
  if (flag[0] != FP32) return;
  __shared__ int s_dst[128];
  __shared__ __align__(16) u16 s_hid[128][136];
  __shared__ __align__(16) u16 s_att[128][16];   // rank-9 A operand, k=0..15 (k9..15 zero)
  int tid = threadIdx.x;
  int ebase = blockIdx.x*128;
  float d0, d1, d2;   // dif kept in registers (all lanes), shfl'd in coord epilogue
  // ---- phase A: el = tid>>1, p = tid&1. epack gives src/dst at level 0; all gathers level 1.
  {
    int el = tid>>1, p = tid&1;
    u32 pk = epack[ebase+el];
    int srcI = (int)(pk & 0xFFFFu), dstI = (int)(pk >> 16);
    int e = perm[ebase+el];
    d0 = IO<FP32>::ld(x, srcI*3+0) - IO<FP32>::ld(x, dstI*3+0);
    d1 = IO<FP32>::ld(x, srcI*3+1) - IO<FP32>::ld(x, dstI*3+1);
    d2 = IO<FP32>::ld(x, srcI*3+2) - IO<FP32>::ld(x, dstI*3+2);
    float dsq = d0*d0 + d1*d1 + d2*d2;
    if (p==0){
      s_dst[el]=dstI;
      float eav[8]; IO<FP32>::ld8(ea, e*8, eav);
      float f9[8];
      f9[0]=dsq; for (int t=0;t<7;t++) f9[1+t]=eav[t];
      *(uint4*)&s_att[el][0] = pack8(f9);
      f9[0]=eav[7]; for (int t=1;t<8;t++) f9[t]=0.f;
      *(uint4*)&s_att[el][8] = pack8(f9);
    }
    const u16* p13r = P13 + srcI*128;
    const u16* p2r  = P2  + dstI*128;
    #pragma unroll
    for (int c=0;c<8;c++){
      int col = p*64 + c*8;
      float fa[8], fb[8];
      cvt8(*(const uint4*)(p13r+col), fa);
      cvt8(*(const uint4*)(p2r+col),  fb);
      #pragma unroll
      for (int i2=0;i2<8;i2++) fa[i2] += fb[i2];
      *(uint4*)&s_hid[el][col] = pack8(fa);
    }
  }
  int lane=tid&63, wid=tid>>6, quad=lane>>4, l15=lane&15;
  int rb = wid*32;
  // ---- rank-9 MFMA, both tiles share Wrk9T fragment loads; quads 2,3 feed zero A-fragments
  f32x4 acc9[2][8];
  #pragma unroll
  for (int t=0;t<2;t++)
    #pragma unroll
    for (int nt=0;nt<8;nt++) acc9[t][nt]=(f32x4){0.f,0.f,0.f,0.f};
  {
    short8 zf = (short8){0,0,0,0,0,0,0,0};
    short8 a90 = zf, a91 = zf;
    if (quad < 2){
      a90 = *(const short8*)&s_att[rb+l15][quad*8];
      a91 = *(const short8*)&s_att[rb+16+l15][quad*8];
    }
    #pragma unroll
    for (int nt=0;nt<8;nt++){
      short8 bfr = *(const short8*)(Wrk9T + (nt*16+l15)*32 + quad*8);
      acc9[0][nt] = __builtin_amdgcn_mfma_f32_16x16x32_bf16(a90, bfr, acc9[0][nt], 0,0,0);
      acc9[1][nt] = __builtin_amdgcn_mfma_f32_16x16x32_bf16(a91, bfr, acc9[1][nt], 0,0,0);
    }
  }
  // ---- fold + silu, both tiles
  #pragma unroll
  for (int t=0;t<2;t++){
    #pragma unroll
    for (int r=0;r<4;r++){
      int row = rb + t*16 + quad*4 + r;
      #pragma unroll
      for (int nt=0;nt<8;nt++){
        int col = nt*16+l15;
        float u = bf2f(s_hid[row][col]) + acc9[t][nt][r];
        u = u*sigmoidf_(u);
        s_hid[row][col] = f2bf(u);
      }
    }
  }
  // ---- GEMM1: m_pre = hid @ We2, tiles share weight loads, ks rolled
  f32x4 acc[2][8];
  #pragma unroll
  for (int t=0;t<2;t++)
    #pragma unroll
    for (int nt=0;nt<8;nt++) acc[t][nt]=(f32x4){0.f,0.f,0.f,0.f};
  #pragma unroll 1
  for (int ks=0;ks<4;ks++){
    short8 af0 = *(const short8*)&s_hid[rb+l15][ks*32+quad*8];
    short8 af1 = *(const short8*)&s_hid[rb+16+l15][ks*32+quad*8];
    #pragma unroll
    for (int nt=0;nt<8;nt++){
      short8 bfr = *(const short8*)(We2T + (nt*16+l15)*128 + ks*32+quad*8);
      acc[0][nt] = __builtin_amdgcn_mfma_f32_16x16x32_bf16(af0, bfr, acc[0][nt], 0,0,0);
      acc[1][nt] = __builtin_amdgcn_mfma_f32_16x16x32_bf16(af1, bfr, acc[1][nt], 0,0,0);
    }
  }
  // ---- epilogue per tile: attention gate, m -> s_hid overlay, run-compressed pk-f16 atomics (R11 inline)
  float b2v[8], wav[8];
  #pragma unroll
  for (int nt=0;nt<8;nt++){ b2v[nt]=IO<FP32>::ld(We2b, nt*16+l15); wav[nt]=IO<FP32>::ld(Watt, nt*16+l15); }
  float attb = IO<FP32>::ld(Wattb, 0);
  #pragma unroll
  for (int t=0;t<2;t++){
    float mval[8][4]; float dotr[4];
    #pragma unroll
    for (int r=0;r<4;r++){
      float s=0.f;
      #pragma unroll
      for (int nt=0;nt<8;nt++){ mval[nt][r]=acc[t][nt][r]+b2v[nt]; s += mval[nt][r]*wav[nt]; }
      dotr[r]=s;
    }
    #pragma unroll
    for (int off=1;off<16;off<<=1){
      #pragma unroll
      for (int r=0;r<4;r++) dotr[r] += __shfl_xor(dotr[r], off);
    }
    float racc[8];
    #pragma unroll
    for (int nt=0;nt<8;nt++) racc[nt]=0.f;
    #pragma unroll
    for (int r=0;r<4;r++){
      float att = sigmoidf_(dotr[r]+attb);
      int erow = rb + t*16 + quad*4 + r;
      int dstN = s_dst[erow];
      bool emit = (r==3) || (s_dst[erow+1] != dstN);
      #pragma unroll
      for (int nt=0;nt<8;nt++){
        float v = mval[nt][r]*att;
        s_hid[erow][nt*16+l15] = f2bf(v);
        racc[nt] += v;
      }
      #pragma unroll
      for (int nt=0;nt<8;nt++){
        float part = __shfl_xor(racc[nt], 1);
        if (emit && ((l15 & 1) == 0)){
          atomic_pk_add_f16(msgh + dstN*128 + nt*16 + l15, f2h2pack(racc[nt], part));
        }
      }
      if (emit){
        #pragma unroll
        for (int nt=0;nt<8;nt++) racc[nt]=0.f;
      }
    }
  }
  // ---- GEMM2: ch_pre = m @ Wx1, tiles share weight loads, ks rolled
  f32x4 acc2[2][8];
  #pragma unroll
  for (int t=0;t<2;t++)
    #pragma unroll
    for (int nt=0;nt<8;nt++) acc2[t][nt]=(f32x4){0.f,0.f,0.f,0.f};
  #pragma unroll 1
  for (int ks=0;ks<4;ks++){
    short8 af0 = *(const short8*)&s_hid[rb+l15][ks*32+quad*8];
    short8 af1 = *(const short8*)&s_hid[rb+16+l15][ks*32+quad*8];
    #pragma unroll
    for (int nt=0;nt<8;nt++){
      short8 bfr = *(const short8*)(Wx1T + (nt*16+l15)*128 + ks*32+quad*8);
      acc2[0][nt] = __builtin_amdgcn_mfma_f32_16x16x32_bf16(af0, bfr, acc2[0][nt], 0,0,0);
      acc2[1][nt] = __builtin_amdgcn_mfma_f32_16x16x32_bf16(af1, bfr, acc2[1][nt], 0,0,0);
    }
  }
  // ---- coord epilogue per tile: dif via shfl from phase-A registers; run-compressed fp32 atomics
  float bx1v[8], wx2v[8];
  #pragma unroll
  for (int nt=0;nt<8;nt++){ bx1v[nt]=IO<FP32>::ld(Wx1b, nt*16+l15); wx2v[nt]=IO<FP32>::ld(Wx2, nt*16+l15); }
  float bx2f = IO<FP32>::ld(Wx2b, 0);
  #pragma unroll
  for (int t=0;t<2;t++){
    float dc[4];
    #pragma unroll
    for (int r=0;r<4;r++){
      float s=0.f;
      #pragma unroll
      for (int nt=0;nt<8;nt++){
        float u = acc2[t][nt][r] + bx1v[nt];
        u = u*sigmoidf_(u);
        s += u*wx2v[nt];
      }
      dc[r]=s;
    }
    #pragma unroll
    for (int off=1;off<16;off<<=1){
      #pragma unroll
      for (int r=0;r<4;r++) dc[r] += __shfl_xor(dc[r], off);
    }
    float c0=0.f, c1=0.f, c2=0.f;
    #pragma unroll
    for (int r=0;r<4;r++){
      float cw = tanhf(dc[r]+bx2f);
      int eloc = t*16 + quad*4 + r;          // wave-local edge row
      int erow = rb + eloc;
      int srcL = 2*eloc;                     // phase-A writer lane for this edge
      float e0 = __shfl(d0, srcL);
      float e1 = __shfl(d1, srcL);
      float e2 = __shfl(d2, srcL);
      c0 += e0*cw; c1 += e1*cw; c2 += e2*cw;
      int dstN = s_dst[erow];
      bool emit = (r==3) || (s_dst[erow+1] != dstN);
      if (emit){
        if (l15==0){
          atomicAdd(&cagg[dstN*4+0], c0);
          atomicAdd(&cagg[dstN*4+1], c1);
          atomicAdd(&cagg[dstN*4+2], c2);
        }
        c0=0.f; c1=0.f; c2=0.f;
      }
    }
  }
}

// ---------------- fused edge kernel, fallback tier (R5/R6-proven, 64 edges/block) ----------------
template<int FP32>
__global__ __launch_bounds__(256, 6) void k_edgeB(
    const int* __restrict__ flag,
    const void* __restrict__ x, const void* __restrict__ ea,
    const void* __restrict__ We1, const void* __restrict__ h,
    const void* __restrict__ We2b, const void* __restrict__ Watt, const void* __restrict__ Wattb,
    const void* __restrict__ Wx1b, const void* __restrict__ Wx2, const void* __restrict__ Wx2b,
    const int* __restrict__ eidx,
    const u16* __restrict__ P13,
    const u16* __restrict__ WprojT,
    const u16* __restrict__ We2T, const u16* __restrict__ Wx1T,
    u16* __restrict__ msgb, float* __restrict__ cagg)
{
  if (flag[0] != FP32) return;
  __shared__ int s_dst[64];
  __shared__ float s_dif[64][3];
  __shared__ __align__(16) u16 s_hid[64][136];
  __shared__ __align__(16) u16 s_m[64][136];
  __shared__ __align__(16) u16 s_hd[64][136];
  int tid = threadIdx.x;
  int ebase = blockIdx.x*64;
  {
    int el = tid>>2, p = tid&3;
    int e = ebase+el;
    int srcI = eidx[e], dstI = eidx[EE+e];
    float d0 = IO<FP32>::ld(x, srcI*3+0) - IO<FP32>::ld(x, dstI*3+0);
    float d1 = IO<FP32>::ld(x, srcI*3+1) - IO<FP32>::ld(x, dstI*3+1);
    float d2 = IO<FP32>::ld(x, srcI*3+2) - IO<FP32>::ld(x, dstI*3+2);
    float dsq = d0*d0 + d1*d1 + d2*d2;
    if (p==0){ s_dst[el]=dstI; s_dif[el][0]=d0; s_dif[el][1]=d1; s_dif[el][2]=d2; }
    float eav[8]; IO<FP32>::ld8(ea, e*8, eav);
    const u16* p13r = P13 + srcI*128;
    #pragma unroll
    for (int c=0;c<4;c++){
      int col = p*32 + c*8;
      float fw[8], pre[8];
      cvt8(*(const uint4*)(p13r+col), pre);
      IO<FP32>::ld8(We1, 256*128 + col, fw);
      #pragma unroll
      for (int i2=0;i2<8;i2++) pre[i2] += dsq*fw[i2];
      #pragma unroll
      for (int t=0;t<8;t++){
        IO<FP32>::ld8(We1, (257+t)*128 + col, fw);
        #pragma unroll
        for (int i2=0;i2<8;i2++) pre[i2] += eav[t]*fw[i2];
      }
      *(uint4*)&s_hid[el][col] = pack8(pre);
      float hd[8]; IO<FP32>::ld8(h, dstI*128 + col, hd);
      *(uint4*)&s_hd[el][col] = pack8(hd);
    }
  }
  int lane=tid&63, wid=tid>>6, quad=lane>>4, l15=lane&15, mb=wid*16;
  {
    f32x4 accg[8];
    #pragma unroll
    for (int nt=0;nt<8;nt++) accg[nt]=(f32x4){0.f,0.f,0.f,0.f};
    #pragma unroll
    for (int ks=0;ks<4;ks++){
      short8 af = *(const short8*)&s_hd[mb+l15][ks*32+quad*8];
      #pragma unroll
      for (int nt=0;nt<8;nt++){
        short8 bfr = *(const short8*)(WprojT + (128 + nt*16+l15)*192 + ks*32+quad*8);
        accg[nt] = __builtin_amdgcn_mfma_f32_16x16x32_bf16(af, bfr, accg[nt], 0,0,0);
      }
    }
    #pragma unroll
    for (int r=0;r<4;r++){
      int row = mb + quad*4 + r;
      #pragma unroll
      for (int nt=0;nt<8;nt++){
        int col = nt*16+l15;
        float u = bf2f(s_hid[row][col]) + accg[nt][r];
        u = u*sigmoidf_(u);
        s_hid[row][col] = f2bf(u);
      }
    }
  }
  f32x4 acc[8];
  #pragma unroll
  for (int nt=0;nt<8;nt++) acc[nt]=(f32x4){0.f,0.f,0.f,0.f};
  #pragma unroll
  for (int ks=0;ks<4;ks++){
    short8 af = *(const short8*)&s_hid[mb+l15][ks*32+quad*8];
    #pragma unroll
    for (int nt=0;nt<8;nt++){
      short8 bfr = *(const short8*)(We2T + (nt*16+l15)*128 + ks*32+quad*8);
      acc[nt] = __builtin_amdgcn_mfma_f32_16x16x32_bf16(af, bfr, acc[nt], 0,0,0);
    }
  }
  float b2v[8], wav[8];
  #pragma unroll
  for (int nt=0;nt<8;nt++){ b2v[nt]=IO<FP32>::ld(We2b, nt*16+l15); wav[nt]=IO<FP32>::ld(Watt, nt*16+l15); }
  float attb = IO<FP32>::ld(Wattb, 0);
  float mval[8][4]; float dotr[4];
  #pragma unroll
  for (int r=0;r<4;r++){
    float s=0.f;
    #pragma unroll
    for (int nt=0;nt<8;nt++){ mval[nt][r]=acc[nt][r]+b2v[nt]; s += mval[nt][r]*wav[nt]; }
    dotr[r]=s;
  }
  #pragma unroll
  for (int off=1;off<16;off<<=1){
    #pragma unroll
    for (int r=0;r<4;r++) dotr[r] += __shfl_xor(dotr[r], off);
  }
  #pragma unroll
  for (int r=0;r<4;r++){
    float att = sigmoidf_(dotr[r]+attb);
    int erow = mb + quad*4 + r;
    int dstN = s_dst[erow];
    #pragma unroll
    for (int nt=0;nt<8;nt++){
      float v = mval[nt][r]*att;
      mval[nt][r] = v;
      s_m[erow][nt*16+l15] = f2bf(v);
    }
    #pragma unroll
    for (int nt=0;nt<8;nt++){
      float part = __shfl_xor(mval[nt][r], 1);
      if ((l15 & 1) == 0){
        atomic_add_bf16pair((u32*)(msgb + dstN*128 + nt*16 + l15), mval[nt][r], part);
      }
    }
  }
  f32x4 acc2[8];
  #pragma unroll
  for (int nt=0;nt<8;nt++) acc2[nt]=(f32x4){0.f,0.f,0.f,0.f};
  #pragma unroll
  for (int ks=0;ks<4;ks++){
    short8 af = *(const short8*)&s_m[mb+l15][ks*32+quad*8];
    #pragma unroll
    for (int nt=0;nt<8;nt++){
      short8 bfr = *(const short8*)(Wx1T + (nt*16+l15)*128 + ks*32+quad*8);
      acc2[nt] = __builtin_amdgcn_mfma_f32_16x16x32_bf16(af, bfr, acc2[nt], 0,0,0);
    }
  }
  float bx1v[8], wx2v[8];
  #pragma unroll
  for (int nt=0;nt<8;nt++){ bx1v[nt]=IO<FP32>::ld(Wx1b, nt*16+l15); wx2v[nt]=IO<FP32>::ld(Wx2, nt*16+l15); }
  float bx2f = IO<FP32>::ld(Wx2b, 0);
  float dc[4];
  #pragma unroll
  for (int r=0;r<4;r++){
    float s=0.f;
    #pragma unroll
    for (int nt=0;nt<8;nt++){
      float u = acc2[nt][r] + bx1v[nt];
      u = u*sigmoidf_(u);
      s += u*wx2v[nt];
    }
    dc[r]=s;
  }
  #pragma unroll
  for (int off=1;off<16;off<<=1){
    #pragma unroll
    for (int r=0;r<4;r++) dc[r] += __shfl_xor(dc[r], off);
  }
  #pragma unroll
  for (int r=0;r<4;r++){
    float cw = tanhf(dc[r]+bx2f);
    if (l15==0){
      int erow = mb + quad*4 + r;
      int dstN = s_dst[erow];
      atomicAdd(&cagg[dstN*4+0], s_dif[erow][0]*cw);
      atomicAdd(&cagg[dstN*4+1], s_dif[erow][1]*cw);
      atomicAdd(&cagg[dstN*4+2], s_dif[erow][2]*cw);
      atomicAdd(&cagg[dstN*4+3], 1.0f);
    }
  }
}

// ---------------- node update ----------------
// MSGF=1: tierA — msg buffer is f16, deg from CSR rowoff. MSGF=0: fallback — bf16 msg, deg from cagg[3].
template<int FP32, int MSGF>
__global__ __launch_bounds__(256) void k_node(
    const int* __restrict__ flag,
    const void* __restrict__ h, const void* __restrict__ x,
    const u16* __restrict__ msgh, const u16* __restrict__ msgb,
    const float* __restrict__ cagg, const int* __restrict__ rowoff,
    const u16* __restrict__ Wh1T, const void* __restrict__ Wh1b,
    const u16* __restrict__ Wh2T, const void* __restrict__ Wh2b,
    void* __restrict__ out)
{
  if (flag[0] != FP32) return;
  __shared__ __align__(16) u16 s_a[64][264];
  __shared__ __align__(16) u16 s_u[64][136];
  int tid = threadIdx.x; int nbase = blockIdx.x*64;
  {
    u32* p1 = (u32*)&s_a[0][0];
    for (int i = tid; i < 8448; i += 256) p1[i] = 0u;
  }
  __syncthreads();
  {
    int r = tid>>2, p = tid&3; int node = nbase + r;
    if (node < NN){
      #pragma unroll
      for (int c=0;c<8;c++){
        int col = p*64 + c*8;
        if (col < 128){
          float f[8]; IO<FP32>::ld8(h, node*128 + col, f);
          *(uint4*)&s_a[r][col] = pack8(f);
        } else if (MSGF){
          uint4 q = *(const uint4*)(msgh + node*128 + (col-128));
          float f[8];
          f[0]=h2f((u16)(q.x&0xFFFF)); f[1]=h2f((u16)(q.x>>16));
          f[2]=h2f((u16)(q.y&0xFFFF)); f[3]=h2f((u16)(q.y>>16));
          f[4]=h2f((u16)(q.z&0xFFFF)); f[5]=h2f((u16)(q.z>>16));
          f[6]=h2f((u16)(q.w&0xFFFF)); f[7]=h2f((u16)(q.w>>16));
          *(uint4*)&s_a[r][col] = pack8(f);
        } else {
          *(uint4*)&s_a[r][col] = *(const uint4*)(msgb + node*128 + (col-128));
        }
      }
    }
  }
  __syncthreads();
  int lane=tid&63, wid=tid>>6, quad=lane>>4, l15=lane&15, mb=wid*16;
  f32x4 acc[8];
  #pragma unroll
  for (int nt=0;nt<8;nt++) acc[nt]=(f32x4){0.f,0.f,0.f,0.f};
  #pragma unroll
  for (int ks=0;ks<8;ks++){
    short8 af = *(const short8*)&s_a[mb+l15][ks*32+quad*8];
    #pragma unroll
    for (int nt=0;nt<8;nt++){
      short8 bfr = *(const short8*)(Wh1T + (nt*16+l15)*256 + ks*32+quad*8);
      acc[nt] = __builtin_amdgcn_mfma_f32_16x16x32_bf16(af, bfr, acc[nt], 0,0,0);
    }
  }
  #pragma unroll
  for (int r=0;r<4;r++){
    int row = mb + quad*4 + r;
    #pragma unroll
    for (int nt=0;nt<8;nt++){
      int col = nt*16+l15;
      float u = acc[nt][r] + IO<FP32>::ld(Wh1b, col);
      u = u*sigmoidf_(u);
      s_u[row][col] = f2bf(u);
    }
  }
  f32x4 acc2[8];
  #pragma unroll
  for (int nt=0;nt<8;nt++) acc2[nt]=(f32x4){0.f,0.f,0.f,0.f};
  #pragma unroll
  for (int ks=0;ks<4;ks++){
    short8 af = *(const short8*)&s_u[mb+l15][ks*32+quad*8];
    #pragma unroll
    for (int nt=0;nt<8;nt++){
      short8 bfr = *(const short8*)(Wh2T + (nt*16+l15)*128 + ks*32+quad*8);
      acc2[nt] = __builtin_amdgcn_mfma_f32_16x16x32_bf16(af, bfr, acc2[nt], 0,0,0);
    }
  }
  #pragma unroll
  for (int r=0;r<4;r++){
    int node = nbase + mb + quad*4 + r;
    if (node < NN){
      #pragma unroll
      for (int nt=0;nt<8;nt++){
        int col = nt*16+l15;
        float v = IO<FP32>::ld(h, node*128+col) + acc2[nt][r] + IO<FP32>::ld(Wh2b, col);
        IO<FP32>::st(out, node*128+col, v);
      }
    }
  }
  if (tid < 64){
    int node = nbase + tid;
    if (node < NN){
      float deg = MSGF ? (float)(rowoff[node+1]-rowoff[node]) : cagg[node*4+3];
      float inv = 1.0f/(deg + 1.0f);
      #pragma unroll
      for (int c=0;c<3;c++){
        float v = IO<FP32>::ld(x, node*3+c) + cagg[node*4+c]*inv;
        IO<FP32>::st(out, NN*128 + node*3 + c, v);
      }
    }
  }
}

extern "C" void kernel_launch(void* const* d_in, const int* in_sizes, int n_in,
                              void* d_out, int out_size, void* d_ws, size_t ws_size,
                              hipStream_t stream) {
  const void* h     = d_in[0];
  const void* x     = d_in[1];
  const void* ea    = d_in[2];
  const void* temb  = d_in[3];
  const void* We1   = d_in[4];
  const void* We1b  = d_in[5];
  const void* We2   = d_in[6];
  const void* We2b  = d_in[7];
  const void* Watt  = d_in[8];
  const void* Wattb = d_in[9];
  const void* Wx1   = d_in[10];
  const void* Wx1b  = d_in[11];
  const void* Wx2   = d_in[12];
  const void* Wx2b  = d_in[13];
  const void* Wh1   = d_in[14];
  const void* Wh1b  = d_in[15];
  const void* Wh2   = d_in[16];
  const void* Wh2b  = d_in[17];
  const int* eidx   = (const int*)d_in[18];
  char* ws = (char*)d_ws;

  u16* WprojT = (u16*)(ws + 0);          //  98,304
  u16* We2T   = (u16*)(ws + 98304);      //  32,768
  u16* Wx1T   = (u16*)(ws + 131072);     //  32,768
  u16* Wh1T   = (u16*)(ws + 163840);     //  65,536
  u16* Wh2T   = (u16*)(ws + 229376);     //  32,768  -> 262,144
  u16* Wrk9T  = (u16*)(ws + 262144);     //   8,192  -> 270,336
  float* cagg = (float*)(ws + 270336);   // 800,000  -> 1,070,336
  int* flag   = (int*)(ws + 1070336);    //     256  -> 1,070,592
  bool tierA = (ws_size >= (size_t)39470592);
  u16* msgh   = (u16*)(ws + 1070592);    // tierA: f16 [NN][128] = 12,800,000 -> 13,870,592
  u16* msgb   = (u16*)(ws + 1070592);    // fallback: bf16 [NN][128]
  u16* P2     = (u16*)(ws + 13870592);   // tierA: 12,800,000 -> 26,670,592
  int* cnt    = (int*)(ws + 26670592);   // 200,704 -> 26,871,296
  int* rowoff = (int*)(ws + 26871296);   // 201,216 -> 27,072,512
  int* cur    = (int*)(ws + 27072512);   // 200,704 -> 27,273,216
  int* bsum   = (int*)(ws + 27273216);   //     256 -> 27,273,472
  int* perm   = (int*)(ws + 27273472);   // 3,200,000 -> 30,473,472
  u32* epack  = (u32*)(ws + 30473472);   // 3,200,000 -> 33,673,472 (R12)
  u16* P13    = (u16*)d_out;

  // zero cagg + flag + msg buffer (13.6 MB)
  hipMemsetAsync(ws + 270336, 0, 13600256, stream);
  k_probe<<<1, 64, 0, stream>>>((const u16*)h, flag);
  if (tierA){
    // CSR sort by dst (dtype-independent)
    hipMemsetAsync(cnt, 0, 200704, stream);
    k_hist<<<(EE+255)/256, 256, 0, stream>>>(eidx, cnt);
    k_scanA<<<SCAN_B, 1024, 0, stream>>>(cnt, rowoff, bsum);
    k_scanB<<<1, 64, 0, stream>>>(bsum);
    k_scanC<<<SCAN_B, 1024, 0, stream>>>(rowoff, cur, bsum);
    k_scatter<<<(EE+255)/256, 256, 0, stream>>>(eidx, cur, perm);
    k_permea<<<(EE+255)/256, 256, 0, stream>>>(eidx, perm, epack);
  }
  k_prep<0><<<528, 256, 0, stream>>>(flag, We1, We2, Wx1, Wh1, Wh2, WprojT, We2T, Wx1T, Wh1T, Wh2T, Wrk9T);
  k_prep<1><<<528, 256, 0, stream>>>(flag, We1, We2, Wx1, Wh1, Wh2, WprojT, We2T, Wx1T, Wh1T, Wh2T, Wrk9T);
  if (tierA){
    k_proj<0,1><<<(NN+63)/64, 256, 0, stream>>>(flag, h, temb, WprojT, We1b, P13, P2);
    k_proj<1,1><<<(NN+63)/64, 256, 0, stream>>>(flag, h, temb, WprojT, We1b, P13, P2);
    k_edgeA<0><<<EE/128, 256, 0, stream>>>(flag, x, ea, We2b, Watt, Wattb, Wx1b, Wx2, Wx2b,
                                           perm, epack, P13, P2, Wrk9T, We2T, Wx1T, msgh, cagg);
    k_edgeA<1><<<EE/128, 256, 0, stream>>>(flag, x, ea, We2b, Watt, Wattb, Wx1b, Wx2, Wx2b,
                                           perm, epack, P13, P2, Wrk9T, We2T, Wx1T, msgh, cagg);
    k_node<0,1><<<(NN+63)/64, 256, 0, stream>>>(flag, h, x, msgh, msgb, cagg, rowoff, Wh1T, Wh1b, Wh2T, Wh2b, d_out);
    k_node<1,1><<<(NN+63)/64, 256, 0, stream>>>(flag, h, x, msgh, msgb, cagg, rowoff, Wh1T, Wh1b, Wh2T, Wh2b, d_out);
  } else {
    k_proj<0,0><<<(NN+63)/64, 256, 0, stream>>>(flag, h, temb, WprojT, We1b, P13, P2);
    k_proj<1,0><<<(NN+63)/64, 256, 0, stream>>>(flag, h, temb, WprojT, We1b, P13, P2);
    k_edgeB<0><<<EE/64, 256, 0, stream>>>(flag, x, ea, We1, h, We2b, Watt, Wattb, Wx1b, Wx2, Wx2b,
                                          eidx, P13, WprojT, We2T, Wx1T, msgb, cagg);
    k_edgeB<1><<<EE/64, 256, 0, stream>>>(flag, x, ea, We1, h, We2b, Watt, Wattb, Wx1b, Wx2, Wx2b,
                                          eidx, P13, WprojT, We2T, Wx1T, msgb, cagg);
    k_node<0,0><<<(NN+63)/64, 256, 0, stream>>>(flag, h, x, msgh, msgb, cagg, rowoff, Wh1T, Wh1b, Wh2T, Wh2b, d_out);
    k_node<1,0><<<(NN+63)/64, 256, 0, stream>>>(flag, h, x, msgh, msgb, cagg, rowoff, Wh1T, Wh1b, Wh2T, Wh2b, d_out);
  }
}

// Round 16
// 814.777 us; speedup vs baseline: 1.0416x; 1.0231x over previous
//
#include <hip/hip_runtime.h>
#include <hip/hip_fp16.h>

typedef unsigned short u16;
typedef unsigned int u32;
typedef __attribute__((ext_vector_type(8))) short short8;
typedef __attribute__((ext_vector_type(4))) float f32x4;

#define NN 50000
#define EE 800000
#define SCAN_B 49   // 49 blocks x 1024 = 50176 >= NN

__device__ __forceinline__ float bf2f(u16 u){ union{u32 i; float f;} v; v.i=((u32)u)<<16; return v.f; }
__device__ __forceinline__ u16 f2bf(float f){ union{float f; u32 i;} v; v.f=f; u32 b=v.i; b += 0x7FFFu + ((b>>16)&1u); return (u16)(b>>16); }
__device__ __forceinline__ float sigmoidf_(float x){ return 1.0f/(1.0f+__expf(-x)); }

__device__ __forceinline__ void cvt8(uint4 q, float* f){
  f[0]=bf2f((u16)(q.x&0xFFFF)); f[1]=bf2f((u16)(q.x>>16));
  f[2]=bf2f((u16)(q.y&0xFFFF)); f[3]=bf2f((u16)(q.y>>16));
  f[4]=bf2f((u16)(q.z&0xFFFF)); f[5]=bf2f((u16)(q.z>>16));
  f[6]=bf2f((u16)(q.w&0xFFFF)); f[7]=bf2f((u16)(q.w>>16));
}
// R11: hardware packed f32->bf16 convert (RNE, identical to f2bf rounding).
__device__ __forceinline__ u32 cvtpk_bf16(float lo, float hi){
  u32 r; asm("v_cvt_pk_bf16_f32 %0, %1, %2" : "=v"(r) : "v"(lo), "v"(hi)); return r;
}
__device__ __forceinline__ uint4 pack8(const float* f){
  uint4 q;
  q.x=cvtpk_bf16(f[0],f[1]);
  q.y=cvtpk_bf16(f[2],f[3]);
  q.z=cvtpk_bf16(f[4],f[5]);
  q.w=cvtpk_bf16(f[6],f[7]);
  return q;
}

// f16 helpers for the packed-f16 atomic message path (R8)
__device__ __forceinline__ float h2f(u16 u){ __half h; *reinterpret_cast<u16*>(&h)=u; return (float)h; }
__device__ __forceinline__ u32 f2h2pack(float lo, float hi){
  __half2 h2 = __floats2half2_rn(lo, hi);
  return *reinterpret_cast<u32*>(&h2);
}
__device__ __forceinline__ void atomic_pk_add_f16(u16* addr, u32 data){
  asm volatile("global_atomic_pk_add_f16 %0, %1, off" :: "v"(addr), "v"(data) : "memory");
}

template<int FP32> struct IO;
template<> struct IO<0> {
  static __device__ __forceinline__ float ld(const void* p, int i){ return bf2f(((const u16*)p)[i]); }
  static __device__ __forceinline__ void ld8(const void* p, int i, float* f){
    cvt8(*(const uint4*)((const u16*)p + i), f);
  }
  static __device__ __forceinline__ void st(void* p, int i, float v){ ((u16*)p)[i] = f2bf(v); }
};
template<> struct IO<1> {
  static __device__ __forceinline__ float ld(const void* p, int i){ return ((const float*)p)[i]; }
  static __device__ __forceinline__ void ld8(const void* p, int i, float* f){
    f32x4 a = *(const f32x4*)((const float*)p + i);
    f32x4 b = *(const f32x4*)((const float*)p + i + 4);
    f[0]=a[0]; f[1]=a[1]; f[2]=a[2]; f[3]=a[3];
    f[4]=b[0]; f[5]=b[1]; f[6]=b[2]; f[7]=b[3];
  }
  static __device__ __forceinline__ void st(void* p, int i, float v){ ((float*)p)[i] = v; }
};

// bf16-pair atomic add via u32 CAS (fallback tier only)
__device__ __forceinline__ void atomic_add_bf16pair(u32* addr, float lo, float hi){
  u32 old = *addr, assumed;
  do {
    assumed = old;
    float flo = bf2f((u16)(assumed & 0xFFFFu)) + lo;
    float fhi = bf2f((u16)(assumed >> 16)) + hi;
    u32 newv = (u32)f2bf(flo) | ((u32)f2bf(fhi) << 16);
    if (newv == assumed) return;
    old = atomicCAS(addr, assumed, newv);
  } while (old != assumed);
}

// ---------------- dtype probe (R14: wave-parallel, same semantics as R4 serial probe) ----------------
__global__ void k_probe(const u16* __restrict__ hraw, int* __restrict__ flag){
  int l = threadIdx.x;   // 64 lanes
  float mx = 0.f; int zc = 0;
  #pragma unroll
  for (int j = 0; j < 2; j++){
    int i = (l + j*64) * 2;          // i = 0,2,...,254
    u16 u = hraw[i];
    if (u == 0) zc++;
    mx = fmaxf(mx, fabsf(bf2f(u)));
  }
  #pragma unroll
  for (int off=1; off<64; off<<=1){
    mx = fmaxf(mx, __shfl_xor(mx, off));
    zc += __shfl_xor(zc, off);
  }
  if (l==0 && blockIdx.x==0) flag[0] = (mx > 1e3f || zc > 32) ? 1 : 0;
}

// ---------------- CSR sort by dst (R9, dtype-independent) ----------------
__global__ __launch_bounds__(256) void k_hist(const int* __restrict__ eidx, int* __restrict__ cnt){
  int e = blockIdx.x*256 + threadIdx.x;
  if (e < EE) atomicAdd(&cnt[eidx[EE+e]], 1);
}
__global__ __launch_bounds__(1024) void k_scanA(const int* __restrict__ cnt,
                                               int* __restrict__ rowoff, int* __restrict__ bsum){
  __shared__ int s[1024];
  int t = threadIdx.x, b = blockIdx.x, i = b*1024 + t;
  int v = (i < NN) ? cnt[i] : 0;
  s[t] = v; __syncthreads();
  #pragma unroll
  for (int off=1; off<1024; off<<=1){
    int add = (t>=off) ? s[t-off] : 0;
    __syncthreads();
    s[t] += add;
    __syncthreads();
  }
  rowoff[i+1] = s[t];              // inclusive chunk scan, pre-offset
  if (t==1023) bsum[b] = s[t];
}
__global__ void k_scanB(int* __restrict__ bsum){
  if (threadIdx.x==0 && blockIdx.x==0){
    int acc=0;
    for (int b=0;b<SCAN_B;b++){ int v=bsum[b]; bsum[b]=acc; acc+=v; }
  }
}
__global__ __launch_bounds__(1024) void k_scanC(int* __restrict__ rowoff, int* __restrict__ cur,
                                               const int* __restrict__ bsum){
  int t = threadIdx.x, b = blockIdx.x, i = b*1024 + t;
  int v = rowoff[i+1] + bsum[b];
  rowoff[i+1] = v;
  if (i < NN-1) cur[i+1] = v;
  if (i==0){ rowoff[0]=0; cur[0]=0; }
}
// R14: scatter also writes epack (fused former k_permea): epack[p] = src | dst<<16.
__global__ __launch_bounds__(256) void k_scatter(const int* __restrict__ eidx,
                                                 int* __restrict__ cur, int* __restrict__ perm,
                                                 u32* __restrict__ epack){
  int e = blockIdx.x*256 + threadIdx.x;
  if (e < EE){
    int dst = eidx[EE+e];
    int p = atomicAdd(&cur[dst], 1);
    perm[p] = e;
    epack[p] = (u32)eidx[e] | ((u32)dst << 16);
  }
}

// ---------------- weight pack (output always bf16) ----------------
template<int FP32>
__global__ __launch_bounds__(256) void k_prep(
    const int* __restrict__ flag,
    const void* __restrict__ We1, const void* __restrict__ We2,
    const void* __restrict__ Wx1, const void* __restrict__ Wh1,
    const void* __restrict__ Wh2,
    u16* __restrict__ WprojT, u16* __restrict__ We2T, u16* __restrict__ Wx1T,
    u16* __restrict__ Wh1T, u16* __restrict__ Wh2T, u16* __restrict__ Wrk9T)
{
  if (flag[0] != FP32) return;
  int i = blockIdx.x*256 + threadIdx.x;
  if (i < 49152){
    int n = i/192, k = i%192; float v;
    if (n < 128) v = (k<128) ? IO<FP32>::ld(We1, k*128+n) : IO<FP32>::ld(We1, (265+k-128)*128+n);
    else         v = (k<128) ? IO<FP32>::ld(We1, (128+k)*128+(n-128)) : 0.f;
    WprojT[i] = f2bf(v);
  } else if (i < 65536){
    int j=i-49152; int n=j/128, k=j%128; We2T[j] = f2bf(IO<FP32>::ld(We2, k*128+n));
  } else if (i < 81920){
    int j=i-65536; int n=j/128, k=j%128; Wx1T[j] = f2bf(IO<FP32>::ld(Wx1, k*128+n));
  } else if (i < 114688){
    int j=i-81920; int n=j/256, k=j%256; Wh1T[j] = f2bf(IO<FP32>::ld(Wh1, k*128+n));
  } else if (i < 131072){
    int j=i-114688; int n=j/128, k=j%128; Wh2T[j] = f2bf(IO<FP32>::ld(Wh2, k*128+n));
  } else if (i < 135168){
    int j=i-131072; int n=j/32, k=j%32;
    float v = (k<=8) ? IO<FP32>::ld(We1, (256+k)*128+n) : 0.f;
    Wrk9T[j] = f2bf(v);
  }
}

// ---------------- P13 (+P2 if WP2) ----------------
template<int FP32, int WP2>
__global__ __launch_bounds__(256) void k_proj(
    const int* __restrict__ flag,
    const void* __restrict__ h, const void* __restrict__ temb,
    const u16* __restrict__ WprojT, const void* __restrict__ We1b,
    u16* __restrict__ P13, u16* __restrict__ P2)
{
  if (flag[0] != FP32) return;
  constexpr int NT = WP2 ? 16 : 8;
  __shared__ __align__(16) u16 s_a[64][200];
  int tid = threadIdx.x; int nbase = blockIdx.x*64;
  {
    u32* p = (u32*)&s_a[0][0];
    for (int i = tid; i < 6400; i += 256) p[i] = 0u;
  }
  __syncthreads();
  {
    int r = tid>>2, p = tid&3; int node = nbase + r;
    if (node < NN){
      #pragma unroll
      for (int c=0;c<6;c++){
        int col = p*48 + c*8;
        float f[8];
        if (col<128) IO<FP32>::ld8(h, node*128 + col, f);
        else         IO<FP32>::ld8(temb, node*64 + (col-128), f);
        *(uint4*)&s_a[r][col] = pack8(f);
      }
    }
  }
  __syncthreads();
  int lane=tid&63, wid=tid>>6, quad=lane>>4, l15=lane&15, mb=wid*16;
  f32x4 acc[NT];
  #pragma unroll
  for (int nt=0;nt<NT;nt++) acc[nt]=(f32x4){0.f,0.f,0.f,0.f};
  #pragma unroll
  for (int ks=0;ks<6;ks++){
    short8 af = *(const short8*)&s_a[mb+l15][ks*32+quad*8];
    #pragma unroll
    for (int nt=0;nt<NT;nt++){
      short8 bfr = *(const short8*)(WprojT + (nt*16+l15)*192 + ks*32+quad*8);
      acc[nt] = __builtin_amdgcn_mfma_f32_16x16x32_bf16(af, bfr, acc[nt], 0,0,0);
    }
  }
  #pragma unroll
  for (int r=0;r<4;r++){
    int node = nbase + mb + quad*4 + r;
    if (node < NN){
      #pragma unroll
      for (int nt=0;nt<NT;nt++){
        int colg = nt*16 + l15;
        float v = acc[nt][r];
        if (colg < 128) P13[node*128+colg] = f2bf(v + IO<FP32>::ld(We1b, colg));
        else if (WP2)   P2[node*128+(colg-128)] = f2bf(v);
      }
    }
  }
}

// ---------------- fused edge kernel, tier A (R13): 128 edges/block, 32 edges/wave, 4 blocks/CU ----
// R13 = R11 k_edgeA + epack phase-A (proven keeper).
template<int FP32>
__global__ __launch_bounds__(256, 4) void k_edgeA(
    const int* __restrict__ flag,
    const void* __restrict__ x, const void* __restrict__ ea,
    const void* __restrict__ We2b, const void* __restrict__ Watt, const void* __restrict__ Wattb,
    const void* __restrict__ Wx1b, const void* __restrict__ Wx2, const void* __restrict__ Wx2b,
    const int* __restrict__ perm, const u32* __restrict__ epack,
    const u16* __restrict__ P13, const u16* __restrict__ P2,
    const u16* __restrict__ Wrk9T, const u16* __restrict__ We2T, const u16* __restrict__ Wx1T,
    u16* __restrict__ msgh, float* __restrict__ cagg)
{
  if (flag[0] != FP32) return;
  __shared__ int s_dst[128];
  __shared__ __align__(16) u16 s_hid[128][136];
  __shared__ __align__(16) u16 s_att[128][16];   // rank-9 A operand, k=0..15 (k9..15 zero)
  int tid = threadIdx.x;
  int ebase = blockIdx.x*128;
  float d0, d1, d2;   // dif kept in registers (all lanes), shfl'd in coord epilogue
  // ---- phase A: el = tid>>1, p = tid&1. epack gives src/dst at level 0; all gathers level 1.
  {
    int el = tid>>1, p = tid&1;
    u32 pk = epack[ebase+el];
    int srcI = (int)(pk & 0xFFFFu), dstI = (int)(pk >> 16);
    int e = perm[ebase+el];
    d0 = IO<FP32>::ld(x, srcI*3+0) - IO<FP32>::ld(x, dstI*3+0);
    d1 = IO<FP32>::ld(x, srcI*3+1) - IO<FP32>::ld(x, dstI*3+1);
    d2 = IO<FP32>::ld(x, srcI*3+2) - IO<FP32>::ld(x, dstI*3+2);
    float dsq = d0*d0 + d1*d1 + d2*d2;
    if (p==0){
      s_dst[el]=dstI;
      float eav[8]; IO<FP32>::ld8(ea, e*8, eav);
      float f9[8];
      f9[0]=dsq; for (int t=0;t<7;t++) f9[1+t]=eav[t];
      *(uint4*)&s_att[el][0] = pack8(f9);
      f9[0]=eav[7]; for (int t=1;t<8;t++) f9[t]=0.f;
      *(uint4*)&s_att[el][8] = pack8(f9);
    }
    const u16* p13r = P13 + srcI*128;
    const u16* p2r  = P2  + dstI*128;
    #pragma unroll
    for (int c=0;c<8;c++){
      int col = p*64 + c*8;
      float fa[8], fb[8];
      cvt8(*(const uint4*)(p13r+col), fa);
      cvt8(*(const uint4*)(p2r+col),  fb);
      #pragma unroll
      for (int i2=0;i2<8;i2++) fa[i2] += fb[i2];
      *(uint4*)&s_hid[el][col] = pack8(fa);
    }
  }
  int lane=tid&63, wid=tid>>6, quad=lane>>4, l15=lane&15;
  int rb = wid*32;
  // ---- rank-9 MFMA, both tiles share Wrk9T fragment loads; quads 2,3 feed zero A-fragments
  f32x4 acc9[2][8];
  #pragma unroll
  for (int t=0;t<2;t++)
    #pragma unroll
    for (int nt=0;nt<8;nt++) acc9[t][nt]=(f32x4){0.f,0.f,0.f,0.f};
  {
    short8 zf = (short8){0,0,0,0,0,0,0,0};
    short8 a90 = zf, a91 = zf;
    if (quad < 2){
      a90 = *(const short8*)&s_att[rb+l15][quad*8];
      a91 = *(const short8*)&s_att[rb+16+l15][quad*8];
    }
    #pragma unroll
    for (int nt=0;nt<8;nt++){
      short8 bfr = *(const short8*)(Wrk9T + (nt*16+l15)*32 + quad*8);
      acc9[0][nt] = __builtin_amdgcn_mfma_f32_16x16x32_bf16(a90, bfr, acc9[0][nt], 0,0,0);
      acc9[1][nt] = __builtin_amdgcn_mfma_f32_16x16x32_bf16(a91, bfr, acc9[1][nt], 0,0,0);
    }
  }
  // ---- fold + silu, both tiles
  #pragma unroll
  for (int t=0;t<2;t++){
    #pragma unroll
    for (int r=0;r<4;r++){
      int row = rb + t*16 + quad*4 + r;
      #pragma unroll
      for (int nt=0;nt<8;nt++){
        int col = nt*16+l15;
        float u = bf2f(s_hid[row][col]) + acc9[t][nt][r];
        u = u*sigmoidf_(u);
        s_hid[row][col] = f2bf(u);
      }
    }
  }
  // ---- GEMM1: m_pre = hid @ We2, tiles share weight loads, ks rolled
  f32x4 acc[2][8];
  #pragma unroll
  for (int t=0;t<2;t++)
    #pragma unroll
    for (int nt=0;nt<8;nt++) acc[t][nt]=(f32x4){0.f,0.f,0.f,0.f};
  #pragma unroll 1
  for (int ks=0;ks<4;ks++){
    short8 af0 = *(const short8*)&s_hid[rb+l15][ks*32+quad*8];
    short8 af1 = *(const short8*)&s_hid[rb+16+l15][ks*32+quad*8];
    #pragma unroll
    for (int nt=0;nt<8;nt++){
      short8 bfr = *(const short8*)(We2T + (nt*16+l15)*128 + ks*32+quad*8);
      acc[0][nt] = __builtin_amdgcn_mfma_f32_16x16x32_bf16(af0, bfr, acc[0][nt], 0,0,0);
      acc[1][nt] = __builtin_amdgcn_mfma_f32_16x16x32_bf16(af1, bfr, acc[1][nt], 0,0,0);
    }
  }
  // ---- epilogue per tile: attention gate, m -> s_hid overlay, run-compressed pk-f16 atomics (inline)
  float b2v[8], wav[8];
  #pragma unroll
  for (int nt=0;nt<8;nt++){ b2v[nt]=IO<FP32>::ld(We2b, nt*16+l15); wav[nt]=IO<FP32>::ld(Watt, nt*16+l15); }
  float attb = IO<FP32>::ld(Wattb, 0);
  #pragma unroll
  for (int t=0;t<2;t++){
    float mval[8][4]; float dotr[4];
    #pragma unroll
    for (int r=0;r<4;r++){
      float s=0.f;
      #pragma unroll
      for (int nt=0;nt<8;nt++){ mval[nt][r]=acc[t][nt][r]+b2v[nt]; s += mval[nt][r]*wav[nt]; }
      dotr[r]=s;
    }
    #pragma unroll
    for (int off=1;off<16;off<<=1){
      #pragma unroll
      for (int r=0;r<4;r++) dotr[r] += __shfl_xor(dotr[r], off);
    }
    float racc[8];
    #pragma unroll
    for (int nt=0;nt<8;nt++) racc[nt]=0.f;
    #pragma unroll
    for (int r=0;r<4;r++){
      float att = sigmoidf_(dotr[r]+attb);
      int erow = rb + t*16 + quad*4 + r;
      int dstN = s_dst[erow];
      bool emit = (r==3) || (s_dst[erow+1] != dstN);
      #pragma unroll
      for (int nt=0;nt<8;nt++){
        float v = mval[nt][r]*att;
        s_hid[erow][nt*16+l15] = f2bf(v);
        racc[nt] += v;
      }
      #pragma unroll
      for (int nt=0;nt<8;nt++){
        float part = __shfl_xor(racc[nt], 1);
        if (emit && ((l15 & 1) == 0)){
          atomic_pk_add_f16(msgh + dstN*128 + nt*16 + l15, f2h2pack(racc[nt], part));
        }
      }
      if (emit){
        #pragma unroll
        for (int nt=0;nt<8;nt++) racc[nt]=0.f;
      }
    }
  }
  // ---- GEMM2: ch_pre = m @ Wx1, tiles share weight loads, ks rolled
  f32x4 acc2[2][8];
  #pragma unroll
  for (int t=0;t<2;t++)
    #pragma unroll
    for (int nt=0;nt<8;nt++) acc2[t][nt]=(f32x4){0.f,0.f,0.f,0.f};
  #pragma unroll 1
  for (int ks=0;ks<4;ks++){
    short8 af0 = *(const short8*)&s_hid[rb+l15][ks*32+quad*8];
    short8 af1 = *(const short8*)&s_hid[rb+16+l15][ks*32+quad*8];
    #pragma unroll
    for (int nt=0;nt<8;nt++){
      short8 bfr = *(const short8*)(Wx1T + (nt*16+l15)*128 + ks*32+quad*8);
      acc2[0][nt] = __builtin_amdgcn_mfma_f32_16x16x32_bf16(af0, bfr, acc2[0][nt], 0,0,0);
      acc2[1][nt] = __builtin_amdgcn_mfma_f32_16x16x32_bf16(af1, bfr, acc2[1][nt], 0,0,0);
    }
  }
  // ---- coord epilogue per tile: dif via shfl from phase-A registers; run-compressed fp32 atomics
  float bx1v[8], wx2v[8];
  #pragma unroll
  for (int nt=0;nt<8;nt++){ bx1v[nt]=IO<FP32>::ld(Wx1b, nt*16+l15); wx2v[nt]=IO<FP32>::ld(Wx2, nt*16+l15); }
  float bx2f = IO<FP32>::ld(Wx2b, 0);
  #pragma unroll
  for (int t=0;t<2;t++){
    float dc[4];
    #pragma unroll
    for (int r=0;r<4;r++){
      float s=0.f;
      #pragma unroll
      for (int nt=0;nt<8;nt++){
        float u = acc2[t][nt][r] + bx1v[nt];
        u = u*sigmoidf_(u);
        s += u*wx2v[nt];
      }
      dc[r]=s;
    }
    #pragma unroll
    for (int off=1;off<16;off<<=1){
      #pragma unroll
      for (int r=0;r<4;r++) dc[r] += __shfl_xor(dc[r], off);
    }
    float c0=0.f, c1=0.f, c2=0.f;
    #pragma unroll
    for (int r=0;r<4;r++){
      float cw = tanhf(dc[r]+bx2f);
      int eloc = t*16 + quad*4 + r;          // wave-local edge row
      int erow = rb + eloc;
      int srcL = 2*eloc;                     // phase-A writer lane for this edge
      float e0 = __shfl(d0, srcL);
      float e1 = __shfl(d1, srcL);
      float e2 = __shfl(d2, srcL);
      c0 += e0*cw; c1 += e1*cw; c2 += e2*cw;
      int dstN = s_dst[erow];
      bool emit = (r==3) || (s_dst[erow+1] != dstN);
      if (emit){
        if (l15==0){
          atomicAdd(&cagg[dstN*4+0], c0);
          atomicAdd(&cagg[dstN*4+1], c1);
          atomicAdd(&cagg[dstN*4+2], c2);
        }
        c0=0.f; c1=0.f; c2=0.f;
      }
    }
  }
}

// ---------------- fused edge kernel, fallback tier (R5/R6-proven, 64 edges/block) ----------------
template<int FP32>
__global__ __launch_bounds__(256, 6) void k_edgeB(
    const int* __restrict__ flag,
    const void* __restrict__ x, const void* __restrict__ ea,
    const void* __restrict__ We1, const void* __restrict__ h,
    const void* __restrict__ We2b, const void* __restrict__ Watt, const void* __restrict__ Wattb,
    const void* __restrict__ Wx1b, const void* __restrict__ Wx2, const void* __restrict__ Wx2b,
    const int* __restrict__ eidx,
    const u16* __restrict__ P13,
    const u16* __restrict__ WprojT,
    const u16* __restrict__ We2T, const u16* __restrict__ Wx1T,
    u16* __restrict__ msgb, float* __restrict__ cagg)
{
  if (flag[0] != FP32) return;
  __shared__ int s_dst[64];
  __shared__ float s_dif[64][3];
  __shared__ __align__(16) u16 s_hid[64][136];
  __shared__ __align__(16) u16 s_m[64][136];
  __shared__ __align__(16) u16 s_hd[64][136];
  int tid = threadIdx.x;
  int ebase = blockIdx.x*64;
  {
    int el = tid>>2, p = tid&3;
    int e = ebase+el;
    int srcI = eidx[e], dstI = eidx[EE+e];
    float d0 = IO<FP32>::ld(x, srcI*3+0) - IO<FP32>::ld(x, dstI*3+0);
    float d1 = IO<FP32>::ld(x, srcI*3+1) - IO<FP32>::ld(x, dstI*3+1);
    float d2 = IO<FP32>::ld(x, srcI*3+2) - IO<FP32>::ld(x, dstI*3+2);
    float dsq = d0*d0 + d1*d1 + d2*d2;
    if (p==0){ s_dst[el]=dstI; s_dif[el][0]=d0; s_dif[el][1]=d1; s_dif[el][2]=d2; }
    float eav[8]; IO<FP32>::ld8(ea, e*8, eav);
    const u16* p13r = P13 + srcI*128;
    #pragma unroll
    for (int c=0;c<4;c++){
      int col = p*32 + c*8;
      float fw[8], pre[8];
      cvt8(*(const uint4*)(p13r+col), pre);
      IO<FP32>::ld8(We1, 256*128 + col, fw);
      #pragma unroll
      for (int i2=0;i2<8;i2++) pre[i2] += dsq*fw[i2];
      #pragma unroll
      for (int t=0;t<8;t++){
        IO<FP32>::ld8(We1, (257+t)*128 + col, fw);
        #pragma unroll
        for (int i2=0;i2<8;i2++) pre[i2] += eav[t]*fw[i2];
      }
      *(uint4*)&s_hid[el][col] = pack8(pre);
      float hd[8]; IO<FP32>::ld8(h, dstI*128 + col, hd);
      *(uint4*)&s_hd[el][col] = pack8(hd);
    }
  }
  int lane=tid&63, wid=tid>>6, quad=lane>>4, l15=lane&15, mb=wid*16;
  {
    f32x4 accg[8];
    #pragma unroll
    for (int nt=0;nt<8;nt++) accg[nt]=(f32x4){0.f,0.f,0.f,0.f};
    #pragma unroll
    for (int ks=0;ks<4;ks++){
      short8 af = *(const short8*)&s_hd[mb+l15][ks*32+quad*8];
      #pragma unroll
      for (int nt=0;nt<8;nt++){
        short8 bfr = *(const short8*)(WprojT + (128 + nt*16+l15)*192 + ks*32+quad*8);
        accg[nt] = __builtin_amdgcn_mfma_f32_16x16x32_bf16(af, bfr, accg[nt], 0,0,0);
      }
    }
    #pragma unroll
    for (int r=0;r<4;r++){
      int row = mb + quad*4 + r;
      #pragma unroll
      for (int nt=0;nt<8;nt++){
        int col = nt*16+l15;
        float u = bf2f(s_hid[row][col]) + accg[nt][r];
        u = u*sigmoidf_(u);
        s_hid[row][col] = f2bf(u);
      }
    }
  }
  f32x4 acc[8];
  #pragma unroll
  for (int nt=0;nt<8;nt++) acc[nt]=(f32x4){0.f,0.f,0.f,0.f};
  #pragma unroll
  for (int ks=0;ks<4;ks++){
    short8 af = *(const short8*)&s_hid[mb+l15][ks*32+quad*8];
    #pragma unroll
    for (int nt=0;nt<8;nt++){
      short8 bfr = *(const short8*)(We2T + (nt*16+l15)*128 + ks*32+quad*8);
      acc[nt] = __builtin_amdgcn_mfma_f32_16x16x32_bf16(af, bfr, acc[nt], 0,0,0);
    }
  }
  float b2v[8], wav[8];
  #pragma unroll
  for (int nt=0;nt<8;nt++){ b2v[nt]=IO<FP32>::ld(We2b, nt*16+l15); wav[nt]=IO<FP32>::ld(Watt, nt*16+l15); }
  float attb = IO<FP32>::ld(Wattb, 0);
  float mval[8][4]; float dotr[4];
  #pragma unroll
  for (int r=0;r<4;r++){
    float s=0.f;
    #pragma unroll
    for (int nt=0;nt<8;nt++){ mval[nt][r]=acc[nt][r]+b2v[nt]; s += mval[nt][r]*wav[nt]; }
    dotr[r]=s;
  }
  #pragma unroll
  for (int off=1;off<16;off<<=1){
    #pragma unroll
    for (int r=0;r<4;r++) dotr[r] += __shfl_xor(dotr[r], off);
  }
  #pragma unroll
  for (int r=0;r<4;r++){
    float att = sigmoidf_(dotr[r]+attb);
    int erow = mb + quad*4 + r;
    int dstN = s_dst[erow];
    #pragma unroll
    for (int nt=0;nt<8;nt++){
      float v = mval[nt][r]*att;
      mval[nt][r] = v;
      s_m[erow][nt*16+l15] = f2bf(v);
    }
    #pragma unroll
    for (int nt=0;nt<8;nt++){
      float part = __shfl_xor(mval[nt][r], 1);
      if ((l15 & 1) == 0){
        atomic_add_bf16pair((u32*)(msgb + dstN*128 + nt*16 + l15), mval[nt][r], part);
      }
    }
  }
  f32x4 acc2[8];
  #pragma unroll
  for (int nt=0;nt<8;nt++) acc2[nt]=(f32x4){0.f,0.f,0.f,0.f};
  #pragma unroll
  for (int ks=0;ks<4;ks++){
    short8 af = *(const short8*)&s_m[mb+l15][ks*32+quad*8];
    #pragma unroll
    for (int nt=0;nt<8;nt++){
      short8 bfr = *(const short8*)(Wx1T + (nt*16+l15)*128 + ks*32+quad*8);
      acc2[nt] = __builtin_amdgcn_mfma_f32_16x16x32_bf16(af, bfr, acc2[nt], 0,0,0);
    }
  }
  float bx1v[8], wx2v[8];
  #pragma unroll
  for (int nt=0;nt<8;nt++){ bx1v[nt]=IO<FP32>::ld(Wx1b, nt*16+l15); wx2v[nt]=IO<FP32>::ld(Wx2, nt*16+l15); }
  float bx2f = IO<FP32>::ld(Wx2b, 0);
  float dc[4];
  #pragma unroll
  for (int r=0;r<4;r++){
    float s=0.f;
    #pragma unroll
    for (int nt=0;nt<8;nt++){
      float u = acc2[nt][r] + bx1v[nt];
      u = u*sigmoidf_(u);
      s += u*wx2v[nt];
    }
    dc[r]=s;
  }
  #pragma unroll
  for (int off=1;off<16;off<<=1){
    #pragma unroll
    for (int r=0;r<4;r++) dc[r] += __shfl_xor(dc[r], off);
  }
  #pragma unroll
  for (int r=0;r<4;r++){
    float cw = tanhf(dc[r]+bx2f);
    if (l15==0){
      int erow = mb + quad*4 + r;
      int dstN = s_dst[erow];
      atomicAdd(&cagg[dstN*4+0], s_dif[erow][0]*cw);
      atomicAdd(&cagg[dstN*4+1], s_dif[erow][1]*cw);
      atomicAdd(&cagg[dstN*4+2], s_dif[erow][2]*cw);
      atomicAdd(&cagg[dstN*4+3], 1.0f);
    }
  }
}

// ---------------- node update ----------------
// MSGF=1: tierA — msg buffer is f16, deg from CSR rowoff. MSGF=0: fallback — bf16 msg, deg from cagg[3].
template<int FP32, int MSGF>
__global__ __launch_bounds__(256) void k_node(
    const int* __restrict__ flag,
    const void* __restrict__ h, const void* __restrict__ x,
    const u16* __restrict__ msgh, const u16* __restrict__ msgb,
    const float* __restrict__ cagg, const int* __restrict__ rowoff,
    const u16* __restrict__ Wh1T, const void* __restrict__ Wh1b,
    const u16* __restrict__ Wh2T, const void* __restrict__ Wh2b,
    void* __restrict__ out)
{
  if (flag[0] != FP32) return;
  __shared__ __align__(16) u16 s_a[64][264];
  __shared__ __align__(16) u16 s_u[64][136];
  int tid = threadIdx.x; int nbase = blockIdx.x*64;
  {
    u32* p1 = (u32*)&s_a[0][0];
    for (int i = tid; i < 8448; i += 256) p1[i] = 0u;
  }
  __syncthreads();
  {
    int r = tid>>2, p = tid&3; int node = nbase + r;
    if (node < NN){
      #pragma unroll
      for (int c=0;c<8;c++){
        int col = p*64 + c*8;
        if (col < 128){
          float f[8]; IO<FP32>::ld8(h, node*128 + col, f);
          *(uint4*)&s_a[r][col] = pack8(f);
        } else if (MSGF){
          uint4 q = *(const uint4*)(msgh + node*128 + (col-128));
          float f[8];
          f[0]=h2f((u16)(q.x&0xFFFF)); f[1]=h2f((u16)(q.x>>16));
          f[2]=h2f((u16)(q.y&0xFFFF)); f[3]=h2f((u16)(q.y>>16));
          f[4]=h2f((u16)(q.z&0xFFFF)); f[5]=h2f((u16)(q.z>>16));
          f[6]=h2f((u16)(q.w&0xFFFF)); f[7]=h2f((u16)(q.w>>16));
          *(uint4*)&s_a[r][col] = pack8(f);
        } else {
          *(uint4*)&s_a[r][col] = *(const uint4*)(msgb + node*128 + (col-128));
        }
      }
    }
  }
  __syncthreads();
  int lane=tid&63, wid=tid>>6, quad=lane>>4, l15=lane&15, mb=wid*16;
  f32x4 acc[8];
  #pragma unroll
  for (int nt=0;nt<8;nt++) acc[nt]=(f32x4){0.f,0.f,0.f,0.f};
  #pragma unroll
  for (int ks=0;ks<8;ks++){
    short8 af = *(const short8*)&s_a[mb+l15][ks*32+quad*8];
    #pragma unroll
    for (int nt=0;nt<8;nt++){
      short8 bfr = *(const short8*)(Wh1T + (nt*16+l15)*256 + ks*32+quad*8);
      acc[nt] = __builtin_amdgcn_mfma_f32_16x16x32_bf16(af, bfr, acc[nt], 0,0,0);
    }
  }
  #pragma unroll
  for (int r=0;r<4;r++){
    int row = mb + quad*4 + r;
    #pragma unroll
    for (int nt=0;nt<8;nt++){
      int col = nt*16+l15;
      float u = acc[nt][r] + IO<FP32>::ld(Wh1b, col);
      u = u*sigmoidf_(u);
      s_u[row][col] = f2bf(u);
    }
  }
  f32x4 acc2[8];
  #pragma unroll
  for (int nt=0;nt<8;nt++) acc2[nt]=(f32x4){0.f,0.f,0.f,0.f};
  #pragma unroll
  for (int ks=0;ks<4;ks++){
    short8 af = *(const short8*)&s_u[mb+l15][ks*32+quad*8];
    #pragma unroll
    for (int nt=0;nt<8;nt++){
      short8 bfr = *(const short8*)(Wh2T + (nt*16+l15)*128 + ks*32+quad*8);
      acc2[nt] = __builtin_amdgcn_mfma_f32_16x16x32_bf16(af, bfr, acc2[nt], 0,0,0);
    }
  }
  #pragma unroll
  for (int r=0;r<4;r++){
    int node = nbase + mb + quad*4 + r;
    if (node < NN){
      #pragma unroll
      for (int nt=0;nt<8;nt++){
        int col = nt*16+l15;
        float v = IO<FP32>::ld(h, node*128+col) + acc2[nt][r] + IO<FP32>::ld(Wh2b, col);
        IO<FP32>::st(out, node*128+col, v);
      }
    }
  }
  if (tid < 64){
    int node = nbase + tid;
    if (node < NN){
      float deg = MSGF ? (float)(rowoff[node+1]-rowoff[node]) : cagg[node*4+3];
      float inv = 1.0f/(deg + 1.0f);
      #pragma unroll
      for (int c=0;c<3;c++){
        float v = IO<FP32>::ld(x, node*3+c) + cagg[node*4+c]*inv;
        IO<FP32>::st(out, NN*128 + node*3 + c, v);
      }
    }
  }
}

extern "C" void kernel_launch(void* const* d_in, const int* in_sizes, int n_in,
                              void* d_out, int out_size, void* d_ws, size_t ws_size,
                              hipStream_t stream) {
  const void* h     = d_in[0];
  const void* x     = d_in[1];
  const void* ea    = d_in[2];
  const void* temb  = d_in[3];
  const void* We1   = d_in[4];
  const void* We1b  = d_in[5];
  const void* We2   = d_in[6];
  const void* We2b  = d_in[7];
  const void* Watt  = d_in[8];
  const void* Wattb = d_in[9];
  const void* Wx1   = d_in[10];
  const void* Wx1b  = d_in[11];
  const void* Wx2   = d_in[12];
  const void* Wx2b  = d_in[13];
  const void* Wh1   = d_in[14];
  const void* Wh1b  = d_in[15];
  const void* Wh2   = d_in[16];
  const void* Wh2b  = d_in[17];
  const int* eidx   = (const int*)d_in[18];
  char* ws = (char*)d_ws;

  u16* WprojT = (u16*)(ws + 0);          //  98,304
  u16* We2T   = (u16*)(ws + 98304);      //  32,768
  u16* Wx1T   = (u16*)(ws + 131072);     //  32,768
  u16* Wh1T   = (u16*)(ws + 163840);     //  65,536
  u16* Wh2T   = (u16*)(ws + 229376);     //  32,768  -> 262,144
  u16* Wrk9T  = (u16*)(ws + 262144);     //   8,192  -> 270,336
  float* cagg = (float*)(ws + 270336);   // 800,000  -> 1,070,336
  int* flag   = (int*)(ws + 1070336);    //     256  -> 1,070,592
  bool tierA = (ws_size >= (size_t)39470592);
  u16* msgh   = (u16*)(ws + 1070592);    // tierA: f16 [NN][128] = 12,800,000 -> 13,870,592
  u16* msgb   = (u16*)(ws + 1070592);    // fallback: bf16 [NN][128]
  u16* P2     = (u16*)(ws + 13870592);   // tierA: 12,800,000 -> 26,670,592
  int* cnt    = (int*)(ws + 26670592);   // 200,704 -> 26,871,296
  int* rowoff = (int*)(ws + 26871296);   // 201,216 -> 27,072,512
  int* cur    = (int*)(ws + 27072512);   // 200,704 -> 27,273,216
  int* bsum   = (int*)(ws + 27273216);   //     256 -> 27,273,472
  int* perm   = (int*)(ws + 27273472);   // 3,200,000 -> 30,473,472
  u32* epack  = (u32*)(ws + 30473472);   // 3,200,000 -> 33,673,472 (R12)
  u16* P13    = (u16*)d_out;

  // zero cagg + flag + msg buffer (13.6 MB)
  hipMemsetAsync(ws + 270336, 0, 13600256, stream);
  k_probe<<<1, 64, 0, stream>>>((const u16*)h, flag);
  if (tierA){
    // CSR sort by dst (dtype-independent); scatter also emits epack (R14 fusion)
    hipMemsetAsync(cnt, 0, 200704, stream);
    k_hist<<<(EE+255)/256, 256, 0, stream>>>(eidx, cnt);
    k_scanA<<<SCAN_B, 1024, 0, stream>>>(cnt, rowoff, bsum);
    k_scanB<<<1, 64, 0, stream>>>(bsum);
    k_scanC<<<SCAN_B, 1024, 0, stream>>>(rowoff, cur, bsum);
    k_scatter<<<(EE+255)/256, 256, 0, stream>>>(eidx, cur, perm, epack);
  }
  k_prep<0><<<528, 256, 0, stream>>>(flag, We1, We2, Wx1, Wh1, Wh2, WprojT, We2T, Wx1T, Wh1T, Wh2T, Wrk9T);
  k_prep<1><<<528, 256, 0, stream>>>(flag, We1, We2, Wx1, Wh1, Wh2, WprojT, We2T, Wx1T, Wh1T, Wh2T, Wrk9T);
  if (tierA){
    k_proj<0,1><<<(NN+63)/64, 256, 0, stream>>>(flag, h, temb, WprojT, We1b, P13, P2);
    k_proj<1,1><<<(NN+63)/64, 256, 0, stream>>>(flag, h, temb, WprojT, We1b, P13, P2);
    k_edgeA<0><<<EE/128, 256, 0, stream>>>(flag, x, ea, We2b, Watt, Wattb, Wx1b, Wx2, Wx2b,
                                           perm, epack, P13, P2, Wrk9T, We2T, Wx1T, msgh, cagg);
    k_edgeA<1><<<EE/128, 256, 0, stream>>>(flag, x, ea, We2b, Watt, Wattb, Wx1b, Wx2, Wx2b,
                                           perm, epack, P13, P2, Wrk9T, We2T, Wx1T, msgh, cagg);
    k_node<0,1><<<(NN+63)/64, 256, 0, stream>>>(flag, h, x, msgh, msgb, cagg, rowoff, Wh1T, Wh1b, Wh2T, Wh2b, d_out);
    k_node<1,1><<<(NN+63)/64, 256, 0, stream>>>(flag, h, x, msgh, msgb, cagg, rowoff, Wh1T, Wh1b, Wh2T, Wh2b, d_out);
  } else {
    k_proj<0,0><<<(NN+63)/64, 256, 0, stream>>>(flag, h, temb, WprojT, We1b, P13, P2);
    k_proj<1,0><<<(NN+63)/64, 256, 0, stream>>>(flag, h, temb, WprojT, We1b, P13, P2);
    k_edgeB<0><<<EE/64, 256, 0, stream>>>(flag, x, ea, We1, h, We2b, Watt, Wattb, Wx1b, Wx2, Wx2b,
                                          eidx, P13, WprojT, We2T, Wx1T, msgb, cagg);
    k_edgeB<1><<<EE/64, 256, 0, stream>>>(flag, x, ea, We1, h, We2b, Watt, Wattb, Wx1b, Wx2, Wx2b,
                                          eidx, P13, WprojT, We2T, Wx1T, msgb, cagg);
    k_node<0,0><<<(NN+63)/64, 256, 0, stream>>>(flag, h, x, msgh, msgb, cagg, rowoff, Wh1T, Wh1b, Wh2T, Wh2b, d_out);
    k_node<1,0><<<(NN+63)/64, 256, 0, stream>>>(flag, h, x, msgh, msgb, cagg, rowoff, Wh1T, Wh1b, Wh2T, Wh2b, d_out);
  }
}

// Round 17
// 804.036 us; speedup vs baseline: 1.0555x; 1.0134x over previous
//
#include <hip/hip_runtime.h>
#include <hip/hip_fp16.h>

typedef unsigned short u16;
typedef unsigned int u32;
typedef __attribute__((ext_vector_type(8))) short short8;
typedef __attribute__((ext_vector_type(4))) float f32x4;

#define NN 50000
#define EE 800000
#define SCAN_B 49   // 49 blocks x 1024 = 50176 >= NN

__device__ __forceinline__ float bf2f(u16 u){ union{u32 i; float f;} v; v.i=((u32)u)<<16; return v.f; }
__device__ __forceinline__ u16 f2bf(float f){ union{float f; u32 i;} v; v.f=f; u32 b=v.i; b += 0x7FFFu + ((b>>16)&1u); return (u16)(b>>16); }
__device__ __forceinline__ float sigmoidf_(float x){ return 1.0f/(1.0f+__expf(-x)); }

__device__ __forceinline__ void cvt8(uint4 q, float* f){
  f[0]=bf2f((u16)(q.x&0xFFFF)); f[1]=bf2f((u16)(q.x>>16));
  f[2]=bf2f((u16)(q.y&0xFFFF)); f[3]=bf2f((u16)(q.y>>16));
  f[4]=bf2f((u16)(q.z&0xFFFF)); f[5]=bf2f((u16)(q.z>>16));
  f[6]=bf2f((u16)(q.w&0xFFFF)); f[7]=bf2f((u16)(q.w>>16));
}
// R11: hardware packed f32->bf16 convert (RNE, identical to f2bf rounding).
__device__ __forceinline__ u32 cvtpk_bf16(float lo, float hi){
  u32 r; asm("v_cvt_pk_bf16_f32 %0, %1, %2" : "=v"(r) : "v"(lo), "v"(hi)); return r;
}
__device__ __forceinline__ uint4 pack8(const float* f){
  uint4 q;
  q.x=cvtpk_bf16(f[0],f[1]);
  q.y=cvtpk_bf16(f[2],f[3]);
  q.z=cvtpk_bf16(f[4],f[5]);
  q.w=cvtpk_bf16(f[6],f[7]);
  return q;
}

// f16 helpers for the packed-f16 atomic message path (R8)
__device__ __forceinline__ float h2f(u16 u){ __half h; *reinterpret_cast<u16*>(&h)=u; return (float)h; }
__device__ __forceinline__ u32 f2h2pack(float lo, float hi){
  __half2 h2 = __floats2half2_rn(lo, hi);
  return *reinterpret_cast<u32*>(&h2);
}
__device__ __forceinline__ void atomic_pk_add_f16(u16* addr, u32 data){
  asm volatile("global_atomic_pk_add_f16 %0, %1, off" :: "v"(addr), "v"(data) : "memory");
}

template<int FP32> struct IO;
template<> struct IO<0> {
  static __device__ __forceinline__ float ld(const void* p, int i){ return bf2f(((const u16*)p)[i]); }
  static __device__ __forceinline__ void ld8(const void* p, int i, float* f){
    cvt8(*(const uint4*)((const u16*)p + i), f);
  }
  static __device__ __forceinline__ void st(void* p, int i, float v){ ((u16*)p)[i] = f2bf(v); }
};
template<> struct IO<1> {
  static __device__ __forceinline__ float ld(const void* p, int i){ return ((const float*)p)[i]; }
  static __device__ __forceinline__ void ld8(const void* p, int i, float* f){
    f32x4 a = *(const f32x4*)((const float*)p + i);
    f32x4 b = *(const f32x4*)((const float*)p + i + 4);
    f[0]=a[0]; f[1]=a[1]; f[2]=a[2]; f[3]=a[3];
    f[4]=b[0]; f[5]=b[1]; f[6]=b[2]; f[7]=b[3];
  }
  static __device__ __forceinline__ void st(void* p, int i, float v){ ((float*)p)[i] = v; }
};
// R15: runtime-dtype scalar load (merged k_prep)
__device__ __forceinline__ float ldrt(int fp, const void* p, int i){
  return fp ? ((const float*)p)[i] : bf2f(((const u16*)p)[i]);
}

// bf16-pair atomic add via u32 CAS (fallback tier only)
__device__ __forceinline__ void atomic_add_bf16pair(u32* addr, float lo, float hi){
  u32 old = *addr, assumed;
  do {
    assumed = old;
    float flo = bf2f((u16)(assumed & 0xFFFFu)) + lo;
    float fhi = bf2f((u16)(assumed >> 16)) + hi;
    u32 newv = (u32)f2bf(flo) | ((u32)f2bf(fhi) << 16);
    if (newv == assumed) return;
    old = atomicCAS(addr, assumed, newv);
  } while (old != assumed);
}

// ---------------- dtype probe (R14: wave-parallel) ----------------
__global__ void k_probe(const u16* __restrict__ hraw, int* __restrict__ flag){
  int l = threadIdx.x;   // 64 lanes
  float mx = 0.f; int zc = 0;
  #pragma unroll
  for (int j = 0; j < 2; j++){
    int i = (l + j*64) * 2;          // i = 0,2,...,254
    u16 u = hraw[i];
    if (u == 0) zc++;
    mx = fmaxf(mx, fabsf(bf2f(u)));
  }
  #pragma unroll
  for (int off=1; off<64; off<<=1){
    mx = fmaxf(mx, __shfl_xor(mx, off));
    zc += __shfl_xor(zc, off);
  }
  if (l==0 && blockIdx.x==0) flag[0] = (mx > 1e3f || zc > 32) ? 1 : 0;
}

// ---------------- CSR sort by dst (R9, dtype-independent) ----------------
__global__ __launch_bounds__(256) void k_hist(const int* __restrict__ eidx, int* __restrict__ cnt){
  int e = blockIdx.x*256 + threadIdx.x;
  if (e < EE) atomicAdd(&cnt[eidx[EE+e]], 1);
}
__global__ __launch_bounds__(1024) void k_scanA(const int* __restrict__ cnt,
                                               int* __restrict__ rowoff, int* __restrict__ bsum){
  __shared__ int s[1024];
  int t = threadIdx.x, b = blockIdx.x, i = b*1024 + t;
  int v = (i < NN) ? cnt[i] : 0;
  s[t] = v; __syncthreads();
  #pragma unroll
  for (int off=1; off<1024; off<<=1){
    int add = (t>=off) ? s[t-off] : 0;
    __syncthreads();
    s[t] += add;
    __syncthreads();
  }
  rowoff[i+1] = s[t];              // inclusive chunk scan, pre-offset
  if (t==1023) bsum[b] = s[t];
}
// R15: scanC with inline exclusive prefix of bsum (k_scanB removed)
__global__ __launch_bounds__(1024) void k_scanC(int* __restrict__ rowoff, int* __restrict__ cur,
                                               const int* __restrict__ bsum){
  __shared__ int s_off;
  int t = threadIdx.x, b = blockIdx.x;
  if (t==0){
    int acc=0;
    for (int j=0;j<b;j++) acc += bsum[j];
    s_off = acc;
  }
  __syncthreads();
  int i = b*1024 + t;
  int v = rowoff[i+1] + s_off;
  rowoff[i+1] = v;
  if (i < NN-1) cur[i+1] = v;
  if (i==0){ rowoff[0]=0; cur[0]=0; }
}
// R14: scatter also writes epack: epack[p] = src | dst<<16.
__global__ __launch_bounds__(256) void k_scatter(const int* __restrict__ eidx,
                                                 int* __restrict__ cur, int* __restrict__ perm,
                                                 u32* __restrict__ epack){
  int e = blockIdx.x*256 + threadIdx.x;
  if (e < EE){
    int dst = eidx[EE+e];
    int p = atomicAdd(&cur[dst], 1);
    perm[p] = e;
    epack[p] = (u32)eidx[e] | ((u32)dst << 16);
  }
}

// ---------------- weight pack (R15: merged dtype, single launch) ----------------
__global__ __launch_bounds__(256) void k_prepM(
    const int* __restrict__ flag,
    const void* __restrict__ We1, const void* __restrict__ We2,
    const void* __restrict__ Wx1, const void* __restrict__ Wh1,
    const void* __restrict__ Wh2,
    u16* __restrict__ WprojT, u16* __restrict__ We2T, u16* __restrict__ Wx1T,
    u16* __restrict__ Wh1T, u16* __restrict__ Wh2T, u16* __restrict__ Wrk9T)
{
  int fp = flag[0];
  int i = blockIdx.x*256 + threadIdx.x;
  if (i < 49152){
    int n = i/192, k = i%192; float v;
    if (n < 128) v = (k<128) ? ldrt(fp, We1, k*128+n) : ldrt(fp, We1, (265+k-128)*128+n);
    else         v = (k<128) ? ldrt(fp, We1, (128+k)*128+(n-128)) : 0.f;
    WprojT[i] = f2bf(v);
  } else if (i < 65536){
    int j=i-49152; int n=j/128, k=j%128; We2T[j] = f2bf(ldrt(fp, We2, k*128+n));
  } else if (i < 81920){
    int j=i-65536; int n=j/128, k=j%128; Wx1T[j] = f2bf(ldrt(fp, Wx1, k*128+n));
  } else if (i < 114688){
    int j=i-81920; int n=j/256, k=j%256; Wh1T[j] = f2bf(ldrt(fp, Wh1, k*128+n));
  } else if (i < 131072){
    int j=i-114688; int n=j/128, k=j%128; Wh2T[j] = f2bf(ldrt(fp, Wh2, k*128+n));
  } else if (i < 135168){
    int j=i-131072; int n=j/32, k=j%32;
    float v = (k<=8) ? ldrt(fp, We1, (256+k)*128+n) : 0.f;
    Wrk9T[j] = f2bf(v);
  }
}

// ---------------- P13 (+P2 if WP2) — R15: merged dtype via inlined body ----------------
template<int FP32, int WP2>
__device__ __forceinline__ void proj_body(
    const void* __restrict__ h, const void* __restrict__ temb,
    const u16* __restrict__ WprojT, const void* __restrict__ We1b,
    u16* __restrict__ P13, u16* __restrict__ P2)
{
  constexpr int NT = WP2 ? 16 : 8;
  __shared__ __align__(16) u16 s_a[64][200];
  int tid = threadIdx.x; int nbase = blockIdx.x*64;
  if (nbase + 64 > NN){                  // R15: zero only needed for rows >= NN (boundary block)
    u32* p = (u32*)&s_a[0][0];
    for (int i = tid; i < 6400; i += 256) p[i] = 0u;
  }
  __syncthreads();
  {
    int r = tid>>2, p = tid&3; int node = nbase + r;
    if (node < NN){
      #pragma unroll
      for (int c=0;c<6;c++){
        int col = p*48 + c*8;
        float f[8];
        if (col<128) IO<FP32>::ld8(h, node*128 + col, f);
        else         IO<FP32>::ld8(temb, node*64 + (col-128), f);
        *(uint4*)&s_a[r][col] = pack8(f);
      }
    }
  }
  __syncthreads();
  int lane=tid&63, wid=tid>>6, quad=lane>>4, l15=lane&15, mb=wid*16;
  f32x4 acc[NT];
  #pragma unroll
  for (int nt=0;nt<NT;nt++) acc[nt]=(f32x4){0.f,0.f,0.f,0.f};
  #pragma unroll
  for (int ks=0;ks<6;ks++){
    short8 af = *(const short8*)&s_a[mb+l15][ks*32+quad*8];
    #pragma unroll
    for (int nt=0;nt<NT;nt++){
      short8 bfr = *(const short8*)(WprojT + (nt*16+l15)*192 + ks*32+quad*8);
      acc[nt] = __builtin_amdgcn_mfma_f32_16x16x32_bf16(af, bfr, acc[nt], 0,0,0);
    }
  }
  #pragma unroll
  for (int r=0;r<4;r++){
    int node = nbase + mb + quad*4 + r;
    if (node < NN){
      #pragma unroll
      for (int nt=0;nt<NT;nt++){
        int colg = nt*16 + l15;
        float v = acc[nt][r];
        if (colg < 128) P13[node*128+colg] = f2bf(v + IO<FP32>::ld(We1b, colg));
        else if (WP2)   P2[node*128+(colg-128)] = f2bf(v);
      }
    }
  }
}
template<int WP2>
__global__ __launch_bounds__(256) void k_projM(
    const int* __restrict__ flag,
    const void* __restrict__ h, const void* __restrict__ temb,
    const u16* __restrict__ WprojT, const void* __restrict__ We1b,
    u16* __restrict__ P13, u16* __restrict__ P2)
{
  if (flag[0] == 0) proj_body<0,WP2>(h, temb, WprojT, We1b, P13, P2);
  else              proj_body<1,WP2>(h, temb, WprojT, We1b, P13, P2);
}

// ---------------- fused edge kernel, tier A (R13, unchanged — control) ----------------
template<int FP32>
__global__ __launch_bounds__(256, 4) void k_edgeA(
    const int* __restrict__ flag,
    const void* __restrict__ x, const void* __restrict__ ea,
    const void* __restrict__ We2b, const void* __restrict__ Watt, const void* __restrict__ Wattb,
    const void* __restrict__ Wx1b, const void* __restrict__ Wx2, const void* __restrict__ Wx2b,
    const int* __restrict__ perm, const u32* __restrict__ epack,
    const u16* __restrict__ P13, const u16* __restrict__ P2,
    const u16* __restrict__ Wrk9T, const u16* __restrict__ We2T, const u16* __restrict__ Wx1T,
    u16* __restrict__ msgh, float* __restrict__ cagg)
{
  if (flag[0] != FP32) return;
  __shared__ int s_dst[128];
  __shared__ __align__(16) u16 s_hid[128][136];
  __shared__ __align__(16) u16 s_att[128][16];   // rank-9 A operand, k=0..15 (k9..15 zero)
  int tid = threadIdx.x;
  int ebase = blockIdx.x*128;
  float d0, d1, d2;   // dif kept in registers (all lanes), shfl'd in coord epilogue
  {
    int el = tid>>1, p = tid&1;
    u32 pk = epack[ebase+el];
    int srcI = (int)(pk & 0xFFFFu), dstI = (int)(pk >> 16);
    int e = perm[ebase+el];
    d0 = IO<FP32>::ld(x, srcI*3+0) - IO<FP32>::ld(x, dstI*3+0);
    d1 = IO<FP32>::ld(x, srcI*3+1) - IO<FP32>::ld(x, dstI*3+1);
    d2 = IO<FP32>::ld(x, srcI*3+2) - IO<FP32>::ld(x, dstI*3+2);
    float dsq = d0*d0 + d1*d1 + d2*d2;
    if (p==0){
      s_dst[el]=dstI;
      float eav[8]; IO<FP32>::ld8(ea, e*8, eav);
      float f9[8];
      f9[0]=dsq; for (int t=0;t<7;t++) f9[1+t]=eav[t];
      *(uint4*)&s_att[el][0] = pack8(f9);
      f9[0]=eav[7]; for (int t=1;t<8;t++) f9[t]=0.f;
      *(uint4*)&s_att[el][8] = pack8(f9);
    }
    const u16* p13r = P13 + srcI*128;
    const u16* p2r  = P2  + dstI*128;
    #pragma unroll
    for (int c=0;c<8;c++){
      int col = p*64 + c*8;
      float fa[8], fb[8];
      cvt8(*(const uint4*)(p13r+col), fa);
      cvt8(*(const uint4*)(p2r+col),  fb);
      #pragma unroll
      for (int i2=0;i2<8;i2++) fa[i2] += fb[i2];
      *(uint4*)&s_hid[el][col] = pack8(fa);
    }
  }
  int lane=tid&63, wid=tid>>6, quad=lane>>4, l15=lane&15;
  int rb = wid*32;
  f32x4 acc9[2][8];
  #pragma unroll
  for (int t=0;t<2;t++)
    #pragma unroll
    for (int nt=0;nt<8;nt++) acc9[t][nt]=(f32x4){0.f,0.f,0.f,0.f};
  {
    short8 zf = (short8){0,0,0,0,0,0,0,0};
    short8 a90 = zf, a91 = zf;
    if (quad < 2){
      a90 = *(const short8*)&s_att[rb+l15][quad*8];
      a91 = *(const short8*)&s_att[rb+16+l15][quad*8];
    }
    #pragma unroll
    for (int nt=0;nt<8;nt++){
      short8 bfr = *(const short8*)(Wrk9T + (nt*16+l15)*32 + quad*8);
      acc9[0][nt] = __builtin_amdgcn_mfma_f32_16x16x32_bf16(a90, bfr, acc9[0][nt], 0,0,0);
      acc9[1][nt] = __builtin_amdgcn_mfma_f32_16x16x32_bf16(a91, bfr, acc9[1][nt], 0,0,0);
    }
  }
  #pragma unroll
  for (int t=0;t<2;t++){
    #pragma unroll
    for (int r=0;r<4;r++){
      int row = rb + t*16 + quad*4 + r;
      #pragma unroll
      for (int nt=0;nt<8;nt++){
        int col = nt*16+l15;
        float u = bf2f(s_hid[row][col]) + acc9[t][nt][r];
        u = u*sigmoidf_(u);
        s_hid[row][col] = f2bf(u);
      }
    }
  }
  f32x4 acc[2][8];
  #pragma unroll
  for (int t=0;t<2;t++)
    #pragma unroll
    for (int nt=0;nt<8;nt++) acc[t][nt]=(f32x4){0.f,0.f,0.f,0.f};
  #pragma unroll 1
  for (int ks=0;ks<4;ks++){
    short8 af0 = *(const short8*)&s_hid[rb+l15][ks*32+quad*8];
    short8 af1 = *(const short8*)&s_hid[rb+16+l15][ks*32+quad*8];
    #pragma unroll
    for (int nt=0;nt<8;nt++){
      short8 bfr = *(const short8*)(We2T + (nt*16+l15)*128 + ks*32+quad*8);
      acc[0][nt] = __builtin_amdgcn_mfma_f32_16x16x32_bf16(af0, bfr, acc[0][nt], 0,0,0);
      acc[1][nt] = __builtin_amdgcn_mfma_f32_16x16x32_bf16(af1, bfr, acc[1][nt], 0,0,0);
    }
  }
  float b2v[8], wav[8];
  #pragma unroll
  for (int nt=0;nt<8;nt++){ b2v[nt]=IO<FP32>::ld(We2b, nt*16+l15); wav[nt]=IO<FP32>::ld(Watt, nt*16+l15); }
  float attb = IO<FP32>::ld(Wattb, 0);
  #pragma unroll
  for (int t=0;t<2;t++){
    float mval[8][4]; float dotr[4];
    #pragma unroll
    for (int r=0;r<4;r++){
      float s=0.f;
      #pragma unroll
      for (int nt=0;nt<8;nt++){ mval[nt][r]=acc[t][nt][r]+b2v[nt]; s += mval[nt][r]*wav[nt]; }
      dotr[r]=s;
    }
    #pragma unroll
    for (int off=1;off<16;off<<=1){
      #pragma unroll
      for (int r=0;r<4;r++) dotr[r] += __shfl_xor(dotr[r], off);
    }
    float racc[8];
    #pragma unroll
    for (int nt=0;nt<8;nt++) racc[nt]=0.f;
    #pragma unroll
    for (int r=0;r<4;r++){
      float att = sigmoidf_(dotr[r]+attb);
      int erow = rb + t*16 + quad*4 + r;
      int dstN = s_dst[erow];
      bool emit = (r==3) || (s_dst[erow+1] != dstN);
      #pragma unroll
      for (int nt=0;nt<8;nt++){
        float v = mval[nt][r]*att;
        s_hid[erow][nt*16+l15] = f2bf(v);
        racc[nt] += v;
      }
      #pragma unroll
      for (int nt=0;nt<8;nt++){
        float part = __shfl_xor(racc[nt], 1);
        if (emit && ((l15 & 1) == 0)){
          atomic_pk_add_f16(msgh + dstN*128 + nt*16 + l15, f2h2pack(racc[nt], part));
        }
      }
      if (emit){
        #pragma unroll
        for (int nt=0;nt<8;nt++) racc[nt]=0.f;
      }
    }
  }
  f32x4 acc2[2][8];
  #pragma unroll
  for (int t=0;t<2;t++)
    #pragma unroll
    for (int nt=0;nt<8;nt++) acc2[t][nt]=(f32x4){0.f,0.f,0.f,0.f};
  #pragma unroll 1
  for (int ks=0;ks<4;ks++){
    short8 af0 = *(const short8*)&s_hid[rb+l15][ks*32+quad*8];
    short8 af1 = *(const short8*)&s_hid[rb+16+l15][ks*32+quad*8];
    #pragma unroll
    for (int nt=0;nt<8;nt++){
      short8 bfr = *(const short8*)(Wx1T + (nt*16+l15)*128 + ks*32+quad*8);
      acc2[0][nt] = __builtin_amdgcn_mfma_f32_16x16x32_bf16(af0, bfr, acc2[0][nt], 0,0,0);
      acc2[1][nt] = __builtin_amdgcn_mfma_f32_16x16x32_bf16(af1, bfr, acc2[1][nt], 0,0,0);
    }
  }
  float bx1v[8], wx2v[8];
  #pragma unroll
  for (int nt=0;nt<8;nt++){ bx1v[nt]=IO<FP32>::ld(Wx1b, nt*16+l15); wx2v[nt]=IO<FP32>::ld(Wx2, nt*16+l15); }
  float bx2f = IO<FP32>::ld(Wx2b, 0);
  #pragma unroll
  for (int t=0;t<2;t++){
    float dc[4];
    #pragma unroll
    for (int r=0;r<4;r++){
      float s=0.f;
      #pragma unroll
      for (int nt=0;nt<8;nt++){
        float u = acc2[t][nt][r] + bx1v[nt];
        u = u*sigmoidf_(u);
        s += u*wx2v[nt];
      }
      dc[r]=s;
    }
    #pragma unroll
    for (int off=1;off<16;off<<=1){
      #pragma unroll
      for (int r=0;r<4;r++) dc[r] += __shfl_xor(dc[r], off);
    }
    float c0=0.f, c1=0.f, c2=0.f;
    #pragma unroll
    for (int r=0;r<4;r++){
      float cw = tanhf(dc[r]+bx2f);
      int eloc = t*16 + quad*4 + r;
      int erow = rb + eloc;
      int srcL = 2*eloc;
      float e0 = __shfl(d0, srcL);
      float e1 = __shfl(d1, srcL);
      float e2 = __shfl(d2, srcL);
      c0 += e0*cw; c1 += e1*cw; c2 += e2*cw;
      int dstN = s_dst[erow];
      bool emit = (r==3) || (s_dst[erow+1] != dstN);
      if (emit){
        if (l15==0){
          atomicAdd(&cagg[dstN*4+0], c0);
          atomicAdd(&cagg[dstN*4+1], c1);
          atomicAdd(&cagg[dstN*4+2], c2);
        }
        c0=0.f; c1=0.f; c2=0.f;
      }
    }
  }
}

// ---------------- fused edge kernel, fallback tier (R5/R6-proven, 64 edges/block) ----------------
template<int FP32>
__global__ __launch_bounds__(256, 6) void k_edgeB(
    const int* __restrict__ flag,
    const void* __restrict__ x, const void* __restrict__ ea,
    const void* __restrict__ We1, const void* __restrict__ h,
    const void* __restrict__ We2b, const void* __restrict__ Watt, const void* __restrict__ Wattb,
    const void* __restrict__ Wx1b, const void* __restrict__ Wx2, const void* __restrict__ Wx2b,
    const int* __restrict__ eidx,
    const u16* __restrict__ P13,
    const u16* __restrict__ WprojT,
    const u16* __restrict__ We2T, const u16* __restrict__ Wx1T,
    u16* __restrict__ msgb, float* __restrict__ cagg)
{
  if (flag[0] != FP32) return;
  __shared__ int s_dst[64];
  __shared__ float s_dif[64][3];
  __shared__ __align__(16) u16 s_hid[64][136];
  __shared__ __align__(16) u16 s_m[64][136];
  __shared__ __align__(16) u16 s_hd[64][136];
  int tid = threadIdx.x;
  int ebase = blockIdx.x*64;
  {
    int el = tid>>2, p = tid&3;
    int e = ebase+el;
    int srcI = eidx[e], dstI = eidx[EE+e];
    float d0 = IO<FP32>::ld(x, srcI*3+0) - IO<FP32>::ld(x, dstI*3+0);
    float d1 = IO<FP32>::ld(x, srcI*3+1) - IO<FP32>::ld(x, dstI*3+1);
    float d2 = IO<FP32>::ld(x, srcI*3+2) - IO<FP32>::ld(x, dstI*3+2);
    float dsq = d0*d0 + d1*d1 + d2*d2;
    if (p==0){ s_dst[el]=dstI; s_dif[el][0]=d0; s_dif[el][1]=d1; s_dif[el][2]=d2; }
    float eav[8]; IO<FP32>::ld8(ea, e*8, eav);
    const u16* p13r = P13 + srcI*128;
    #pragma unroll
    for (int c=0;c<4;c++){
      int col = p*32 + c*8;
      float fw[8], pre[8];
      cvt8(*(const uint4*)(p13r+col), pre);
      IO<FP32>::ld8(We1, 256*128 + col, fw);
      #pragma unroll
      for (int i2=0;i2<8;i2++) pre[i2] += dsq*fw[i2];
      #pragma unroll
      for (int t=0;t<8;t++){
        IO<FP32>::ld8(We1, (257+t)*128 + col, fw);
        #pragma unroll
        for (int i2=0;i2<8;i2++) pre[i2] += eav[t]*fw[i2];
      }
      *(uint4*)&s_hid[el][col] = pack8(pre);
      float hd[8]; IO<FP32>::ld8(h, dstI*128 + col, hd);
      *(uint4*)&s_hd[el][col] = pack8(hd);
    }
  }
  int lane=tid&63, wid=tid>>6, quad=lane>>4, l15=lane&15, mb=wid*16;
  {
    f32x4 accg[8];
    #pragma unroll
    for (int nt=0;nt<8;nt++) accg[nt]=(f32x4){0.f,0.f,0.f,0.f};
    #pragma unroll
    for (int ks=0;ks<4;ks++){
      short8 af = *(const short8*)&s_hd[mb+l15][ks*32+quad*8];
      #pragma unroll
      for (int nt=0;nt<8;nt++){
        short8 bfr = *(const short8*)(WprojT + (128 + nt*16+l15)*192 + ks*32+quad*8);
        accg[nt] = __builtin_amdgcn_mfma_f32_16x16x32_bf16(af, bfr, accg[nt], 0,0,0);
      }
    }
    #pragma unroll
    for (int r=0;r<4;r++){
      int row = mb + quad*4 + r;
      #pragma unroll
      for (int nt=0;nt<8;nt++){
        int col = nt*16+l15;
        float u = bf2f(s_hid[row][col]) + accg[nt][r];
        u = u*sigmoidf_(u);
        s_hid[row][col] = f2bf(u);
      }
    }
  }
  f32x4 acc[8];
  #pragma unroll
  for (int nt=0;nt<8;nt++) acc[nt]=(f32x4){0.f,0.f,0.f,0.f};
  #pragma unroll
  for (int ks=0;ks<4;ks++){
    short8 af = *(const short8*)&s_hid[mb+l15][ks*32+quad*8];
    #pragma unroll
    for (int nt=0;nt<8;nt++){
      short8 bfr = *(const short8*)(We2T + (nt*16+l15)*128 + ks*32+quad*8);
      acc[nt] = __builtin_amdgcn_mfma_f32_16x16x32_bf16(af, bfr, acc[nt], 0,0,0);
    }
  }
  float b2v[8], wav[8];
  #pragma unroll
  for (int nt=0;nt<8;nt++){ b2v[nt]=IO<FP32>::ld(We2b, nt*16+l15); wav[nt]=IO<FP32>::ld(Watt, nt*16+l15); }
  float attb = IO<FP32>::ld(Wattb, 0);
  float mval[8][4]; float dotr[4];
  #pragma unroll
  for (int r=0;r<4;r++){
    float s=0.f;
    #pragma unroll
    for (int nt=0;nt<8;nt++){ mval[nt][r]=acc[nt][r]+b2v[nt]; s += mval[nt][r]*wav[nt]; }
    dotr[r]=s;
  }
  #pragma unroll
  for (int off=1;off<16;off<<=1){
    #pragma unroll
    for (int r=0;r<4;r++) dotr[r] += __shfl_xor(dotr[r], off);
  }
  #pragma unroll
  for (int r=0;r<4;r++){
    float att = sigmoidf_(dotr[r]+attb);
    int erow = mb + quad*4 + r;
    int dstN = s_dst[erow];
    #pragma unroll
    for (int nt=0;nt<8;nt++){
      float v = mval[nt][r]*att;
      mval[nt][r] = v;
      s_m[erow][nt*16+l15] = f2bf(v);
    }
    #pragma unroll
    for (int nt=0;nt<8;nt++){
      float part = __shfl_xor(mval[nt][r], 1);
      if ((l15 & 1) == 0){
        atomic_add_bf16pair((u32*)(msgb + dstN*128 + nt*16 + l15), mval[nt][r], part);
      }
    }
  }
  f32x4 acc2[8];
  #pragma unroll
  for (int nt=0;nt<8;nt++) acc2[nt]=(f32x4){0.f,0.f,0.f,0.f};
  #pragma unroll
  for (int ks=0;ks<4;ks++){
    short8 af = *(const short8*)&s_m[mb+l15][ks*32+quad*8];
    #pragma unroll
    for (int nt=0;nt<8;nt++){
      short8 bfr = *(const short8*)(Wx1T + (nt*16+l15)*128 + ks*32+quad*8);
      acc2[nt] = __builtin_amdgcn_mfma_f32_16x16x32_bf16(af, bfr, acc2[nt], 0,0,0);
    }
  }
  float bx1v[8], wx2v[8];
  #pragma unroll
  for (int nt=0;nt<8;nt++){ bx1v[nt]=IO<FP32>::ld(Wx1b, nt*16+l15); wx2v[nt]=IO<FP32>::ld(Wx2, nt*16+l15); }
  float bx2f = IO<FP32>::ld(Wx2b, 0);
  float dc[4];
  #pragma unroll
  for (int r=0;r<4;r++){
    float s=0.f;
    #pragma unroll
    for (int nt=0;nt<8;nt++){
      float u = acc2[nt][r] + bx1v[nt];
      u = u*sigmoidf_(u);
      s += u*wx2v[nt];
    }
    dc[r]=s;
  }
  #pragma unroll
  for (int off=1;off<16;off<<=1){
    #pragma unroll
    for (int r=0;r<4;r++) dc[r] += __shfl_xor(dc[r], off);
  }
  #pragma unroll
  for (int r=0;r<4;r++){
    float cw = tanhf(dc[r]+bx2f);
    if (l15==0){
      int erow = mb + quad*4 + r;
      int dstN = s_dst[erow];
      atomicAdd(&cagg[dstN*4+0], s_dif[erow][0]*cw);
      atomicAdd(&cagg[dstN*4+1], s_dif[erow][1]*cw);
      atomicAdd(&cagg[dstN*4+2], s_dif[erow][2]*cw);
      atomicAdd(&cagg[dstN*4+3], 1.0f);
    }
  }
}

// ---------------- node update — R15: merged dtype via inlined body ----------------
template<int FP32, int MSGF>
__device__ __forceinline__ void node_body(
    const void* __restrict__ h, const void* __restrict__ x,
    const u16* __restrict__ msgh, const u16* __restrict__ msgb,
    const float* __restrict__ cagg, const int* __restrict__ rowoff,
    const u16* __restrict__ Wh1T, const void* __restrict__ Wh1b,
    const u16* __restrict__ Wh2T, const void* __restrict__ Wh2b,
    void* __restrict__ out)
{
  __shared__ __align__(16) u16 s_a[64][264];
  __shared__ __align__(16) u16 s_u[64][136];
  int tid = threadIdx.x; int nbase = blockIdx.x*64;
  if (nbase + 64 > NN){                  // R15: zero only needed for rows >= NN (boundary block)
    u32* p1 = (u32*)&s_a[0][0];
    for (int i = tid; i < 8448; i += 256) p1[i] = 0u;
  }
  __syncthreads();
  {
    int r = tid>>2, p = tid&3; int node = nbase + r;
    if (node < NN){
      #pragma unroll
      for (int c=0;c<8;c++){
        int col = p*64 + c*8;
        if (col < 128){
          float f[8]; IO<FP32>::ld8(h, node*128 + col, f);
          *(uint4*)&s_a[r][col] = pack8(f);
        } else if (MSGF){
          uint4 q = *(const uint4*)(msgh + node*128 + (col-128));
          float f[8];
          f[0]=h2f((u16)(q.x&0xFFFF)); f[1]=h2f((u16)(q.x>>16));
          f[2]=h2f((u16)(q.y&0xFFFF)); f[3]=h2f((u16)(q.y>>16));
          f[4]=h2f((u16)(q.z&0xFFFF)); f[5]=h2f((u16)(q.z>>16));
          f[6]=h2f((u16)(q.w&0xFFFF)); f[7]=h2f((u16)(q.w>>16));
          *(uint4*)&s_a[r][col] = pack8(f);
        } else {
          *(uint4*)&s_a[r][col] = *(const uint4*)(msgb + node*128 + (col-128));
        }
      }
    }
  }
  __syncthreads();
  int lane=tid&63, wid=tid>>6, quad=lane>>4, l15=lane&15, mb=wid*16;
  f32x4 acc[8];
  #pragma unroll
  for (int nt=0;nt<8;nt++) acc[nt]=(f32x4){0.f,0.f,0.f,0.f};
  #pragma unroll
  for (int ks=0;ks<8;ks++){
    short8 af = *(const short8*)&s_a[mb+l15][ks*32+quad*8];
    #pragma unroll
    for (int nt=0;nt<8;nt++){
      short8 bfr = *(const short8*)(Wh1T + (nt*16+l15)*256 + ks*32+quad*8);
      acc[nt] = __builtin_amdgcn_mfma_f32_16x16x32_bf16(af, bfr, acc[nt], 0,0,0);
    }
  }
  #pragma unroll
  for (int r=0;r<4;r++){
    int row = mb + quad*4 + r;
    #pragma unroll
    for (int nt=0;nt<8;nt++){
      int col = nt*16+l15;
      float u = acc[nt][r] + IO<FP32>::ld(Wh1b, col);
      u = u*sigmoidf_(u);
      s_u[row][col] = f2bf(u);
    }
  }
  f32x4 acc2[8];
  #pragma unroll
  for (int nt=0;nt<8;nt++) acc2[nt]=(f32x4){0.f,0.f,0.f,0.f};
  #pragma unroll
  for (int ks=0;ks<4;ks++){
    short8 af = *(const short8*)&s_u[mb+l15][ks*32+quad*8];
    #pragma unroll
    for (int nt=0;nt<8;nt++){
      short8 bfr = *(const short8*)(Wh2T + (nt*16+l15)*128 + ks*32+quad*8);
      acc2[nt] = __builtin_amdgcn_mfma_f32_16x16x32_bf16(af, bfr, acc2[nt], 0,0,0);
    }
  }
  #pragma unroll
  for (int r=0;r<4;r++){
    int node = nbase + mb + quad*4 + r;
    if (node < NN){
      #pragma unroll
      for (int nt=0;nt<8;nt++){
        int col = nt*16+l15;
        float v = IO<FP32>::ld(h, node*128+col) + acc2[nt][r] + IO<FP32>::ld(Wh2b, col);
        IO<FP32>::st(out, node*128+col, v);
      }
    }
  }
  if (tid < 64){
    int node = nbase + tid;
    if (node < NN){
      float deg = MSGF ? (float)(rowoff[node+1]-rowoff[node]) : cagg[node*4+3];
      float inv = 1.0f/(deg + 1.0f);
      #pragma unroll
      for (int c=0;c<3;c++){
        float v = IO<FP32>::ld(x, node*3+c) + cagg[node*4+c]*inv;
        IO<FP32>::st(out, NN*128 + node*3 + c, v);
      }
    }
  }
}
template<int MSGF>
__global__ __launch_bounds__(256) void k_nodeM(
    const int* __restrict__ flag,
    const void* __restrict__ h, const void* __restrict__ x,
    const u16* __restrict__ msgh, const u16* __restrict__ msgb,
    const float* __restrict__ cagg, const int* __restrict__ rowoff,
    const u16* __restrict__ Wh1T, const void* __restrict__ Wh1b,
    const u16* __restrict__ Wh2T, const void* __restrict__ Wh2b,
    void* __restrict__ out)
{
  if (flag[0] == 0) node_body<0,MSGF>(h, x, msgh, msgb, cagg, rowoff, Wh1T, Wh1b, Wh2T, Wh2b, out);
  else              node_body<1,MSGF>(h, x, msgh, msgb, cagg, rowoff, Wh1T, Wh1b, Wh2T, Wh2b, out);
}

extern "C" void kernel_launch(void* const* d_in, const int* in_sizes, int n_in,
                              void* d_out, int out_size, void* d_ws, size_t ws_size,
                              hipStream_t stream) {
  const void* h     = d_in[0];
  const void* x     = d_in[1];
  const void* ea    = d_in[2];
  const void* temb  = d_in[3];
  const void* We1   = d_in[4];
  const void* We1b  = d_in[5];
  const void* We2   = d_in[6];
  const void* We2b  = d_in[7];
  const void* Watt  = d_in[8];
  const void* Wattb = d_in[9];
  const void* Wx1   = d_in[10];
  const void* Wx1b  = d_in[11];
  const void* Wx2   = d_in[12];
  const void* Wx2b  = d_in[13];
  const void* Wh1   = d_in[14];
  const void* Wh1b  = d_in[15];
  const void* Wh2   = d_in[16];
  const void* Wh2b  = d_in[17];
  const int* eidx   = (const int*)d_in[18];
  char* ws = (char*)d_ws;

  u16* WprojT = (u16*)(ws + 0);          //  98,304
  u16* We2T   = (u16*)(ws + 98304);      //  32,768
  u16* Wx1T   = (u16*)(ws + 131072);     //  32,768
  u16* Wh1T   = (u16*)(ws + 163840);     //  65,536
  u16* Wh2T   = (u16*)(ws + 229376);     //  32,768  -> 262,144
  u16* Wrk9T  = (u16*)(ws + 262144);     //   8,192  -> 270,336
  float* cagg = (float*)(ws + 270336);   // 800,000  -> 1,070,336
  int* flag   = (int*)(ws + 1070336);    //     256  -> 1,070,592
  bool tierA = (ws_size >= (size_t)39470592);
  u16* msgh   = (u16*)(ws + 1070592);    // tierA: f16 [NN][128] = 12,800,000 -> 13,870,592
  u16* msgb   = (u16*)(ws + 1070592);    // fallback: bf16 [NN][128]
  u16* P2     = (u16*)(ws + 13870592);   // tierA: 12,800,000 -> 26,670,592
  int* cnt    = (int*)(ws + 26670592);   // 200,704 -> 26,871,296
  int* rowoff = (int*)(ws + 26871296);   // 201,216 -> 27,072,512
  int* cur    = (int*)(ws + 27072512);   // 200,704 -> 27,273,216
  int* bsum   = (int*)(ws + 27273216);   //     256 -> 27,273,472
  int* perm   = (int*)(ws + 27273472);   // 3,200,000 -> 30,473,472
  u32* epack  = (u32*)(ws + 30473472);   // 3,200,000 -> 33,673,472 (R12)
  u16* P13    = (u16*)d_out;

  // zero cagg + flag + msg buffer (13.6 MB)
  hipMemsetAsync(ws + 270336, 0, 13600256, stream);
  k_probe<<<1, 64, 0, stream>>>((const u16*)h, flag);
  if (tierA){
    // CSR sort by dst; scatter also emits epack (R14 fusion); scanB folded into scanC (R15)
    hipMemsetAsync(cnt, 0, 200704, stream);
    k_hist<<<(EE+255)/256, 256, 0, stream>>>(eidx, cnt);
    k_scanA<<<SCAN_B, 1024, 0, stream>>>(cnt, rowoff, bsum);
    k_scanC<<<SCAN_B, 1024, 0, stream>>>(rowoff, cur, bsum);
    k_scatter<<<(EE+255)/256, 256, 0, stream>>>(eidx, cur, perm, epack);
  }
  k_prepM<<<528, 256, 0, stream>>>(flag, We1, We2, Wx1, Wh1, Wh2, WprojT, We2T, Wx1T, Wh1T, Wh2T, Wrk9T);
  if (tierA){
    k_projM<1><<<(NN+63)/64, 256, 0, stream>>>(flag, h, temb, WprojT, We1b, P13, P2);
    k_edgeA<0><<<EE/128, 256, 0, stream>>>(flag, x, ea, We2b, Watt, Wattb, Wx1b, Wx2, Wx2b,
                                           perm, epack, P13, P2, Wrk9T, We2T, Wx1T, msgh, cagg);
    k_edgeA<1><<<EE/128, 256, 0, stream>>>(flag, x, ea, We2b, Watt, Wattb, Wx1b, Wx2, Wx2b,
                                           perm, epack, P13, P2, Wrk9T, We2T, Wx1T, msgh, cagg);
    k_nodeM<1><<<(NN+63)/64, 256, 0, stream>>>(flag, h, x, msgh, msgb, cagg, rowoff, Wh1T, Wh1b, Wh2T, Wh2b, d_out);
  } else {
    k_projM<0><<<(NN+63)/64, 256, 0, stream>>>(flag, h, temb, WprojT, We1b, P13, P2);
    k_edgeB<0><<<EE/64, 256, 0, stream>>>(flag, x, ea, We1, h, We2b, Watt, Wattb, Wx1b, Wx2, Wx2b,
                                          eidx, P13, WprojT, We2T, Wx1T, msgb, cagg);
    k_edgeB<1><<<EE/64, 256, 0, stream>>>(flag, x, ea, We1, h, We2b, Watt, Wattb, Wx1b, Wx2, Wx2b,
                                          eidx, P13, WprojT, We2T, Wx1T, msgb, cagg);
    k_nodeM<0><<<(NN+63)/64, 256, 0, stream>>>(flag, h, x, msgh, msgb, cagg, rowoff, Wh1T, Wh1b, Wh2T, Wh2b, d_out);
  }
}